// Round 9
// baseline (1806.975 us; speedup 1.0000x reference)
//
#include <hip/hip_runtime.h>
#include <cstdint>
#include <cstddef>

#define BB 8
#define TT 128
#define LL 12
#define HH 768
#define NHH 12
#define DHH 64
#define FFI 3072
#define KT 5
#define START_TAG 3
#define MTOK (BB*TT)   // 1024

// per-layer plane strides (elements)
#define LQS 1769472u   // 768*2304
#define LOS 589824u    // 768*768
#define L1S 2359296u   // 768*3072
#define L2S 2359296u   // 3072*768

typedef _Float16 f16x8 __attribute__((ext_vector_type(8)));
typedef _Float16 f16x4 __attribute__((ext_vector_type(4)));
typedef float f32x4 __attribute__((ext_vector_type(4)));

__device__ __forceinline__ void gl_lds16(const _Float16* g, _Float16* l) {
    __builtin_amdgcn_global_load_lds(
        (const __attribute__((address_space(1))) unsigned int*)g,
        (__attribute__((address_space(3))) unsigned int*)l, 16, 0, 0);
}

__device__ __forceinline__ float gelu_f(float x) {
    float c = 0.7978845608028654f * (x + 0.044715f * x * x * x);
    return 0.5f * x * (1.f + tanhf(c));
}

// write one 8-elem chunk of a normalized row into A-plane tiles (K=768, kTiles=24)
__device__ __forceinline__ void write_h_planes(const float* rowbuf, int tok,
                                               _Float16* dh, _Float16* dl, int c) {
    int kb = c >> 2;
    int rowm = tok & 127, mb = tok >> 7;
    int koct = c & 3;
    int p = rowm * 4 + (koct ^ (rowm & 3));
    size_t tb = ((size_t)(mb * 24 + kb)) * 4096;
    f16x8 vh, vl;
#pragma unroll
    for (int j = 0; j < 8; ++j) {
        float x = rowbuf[c * 8 + j];
        _Float16 hi = (_Float16)x;
        vh[j] = hi;
        vl[j] = (_Float16)((x - (float)hi) * 4096.f);
    }
    *(f16x8*)(dh + tb + (size_t)p * 8) = vh;
    *(f16x8*)(dl + tb + (size_t)p * 8) = vl;
}

// ---------------- embedding + LN (+A-plane emit) ----------------
__global__ __launch_bounds__(256) void embed_ln_kernel(
    const int* __restrict__ sentence,
    const float* __restrict__ word_emb,
    const float* __restrict__ pos_emb,
    const float* __restrict__ type_emb,
    const float* __restrict__ ln_s,
    const float* __restrict__ ln_b,
    float* __restrict__ h,
    _Float16* __restrict__ dh, _Float16* __restrict__ dl)
{
    int tok = blockIdx.x;
    int t = tok % TT;
    int id = sentence[tok];
    const float* we = word_emb + (size_t)id * HH;
    const float* pe = pos_emb + (size_t)t * HH;

    __shared__ float rowbuf[HH];
    __shared__ float rs_[4], rss_[4];
    float x[3];
    float s = 0.f, ss = 0.f;
#pragma unroll
    for (int i = 0; i < 3; ++i) {
        int d = threadIdx.x + i * 256;
        float v = we[d] + pe[d] + type_emb[d];
        x[i] = v; s += v; ss += v * v;
    }
    for (int o = 32; o; o >>= 1) { s += __shfl_down(s, o); ss += __shfl_down(ss, o); }
    int wid = threadIdx.x >> 6;
    if ((threadIdx.x & 63) == 0) { rs_[wid] = s; rss_[wid] = ss; }
    __syncthreads();
    s = rs_[0] + rs_[1] + rs_[2] + rs_[3];
    ss = rss_[0] + rss_[1] + rss_[2] + rss_[3];
    float mean = s * (1.f / HH);
    float var = ss * (1.f / HH) - mean * mean;
    float rstd = rsqrtf(var + 1e-12f);
#pragma unroll
    for (int i = 0; i < 3; ++i) {
        int d = threadIdx.x + i * 256;
        float y = (x[i] - mean) * rstd * ln_s[d] + ln_b[d];
        h[(size_t)tok * HH + d] = y;
        rowbuf[d] = y;
    }
    __syncthreads();
    if (threadIdx.x < 96) write_h_planes(rowbuf, tok, dh, dl, threadIdx.x);
}

// ---------------- split-K reduce + bias + residual + LN (+A-plane emit OR feats) ----------------
template<int FEATS>
__global__ __launch_bounds__(256) void add_ln_red_kernel(
    float* __restrict__ h, const float* __restrict__ parts,
    const float* __restrict__ bias,
    const float* __restrict__ ln_s, const float* __restrict__ ln_b,
    _Float16* __restrict__ dh, _Float16* __restrict__ dl,
    const float* __restrict__ Wt, const float* __restrict__ bt,
    float* __restrict__ feats)
{
    int tok = blockIdx.x;
    __shared__ float rowbuf[HH];
    __shared__ float rs_[4], rss_[4];
    float x[3];
    float s = 0.f, ss = 0.f;
#pragma unroll
    for (int i = 0; i < 3; ++i) {
        int d = threadIdx.x + i * 256;
        size_t idx = (size_t)tok * HH + d;
        float delta = parts[idx] + parts[idx + (size_t)MTOK * HH]
                    + parts[idx + 2 * (size_t)MTOK * HH] + parts[idx + 3 * (size_t)MTOK * HH]
                    + bias[d];
        float v = h[idx] + delta;
        x[i] = v; s += v; ss += v * v;
    }
    for (int o = 32; o; o >>= 1) { s += __shfl_down(s, o); ss += __shfl_down(ss, o); }
    int wid = threadIdx.x >> 6;
    if ((threadIdx.x & 63) == 0) { rs_[wid] = s; rss_[wid] = ss; }
    __syncthreads();
    s = rs_[0] + rs_[1] + rs_[2] + rs_[3];
    ss = rss_[0] + rss_[1] + rss_[2] + rss_[3];
    float mean = s * (1.f / HH);
    float var = ss * (1.f / HH) - mean * mean;
    float rstd = rsqrtf(var + 1e-12f);
    float yv[3];
#pragma unroll
    for (int i = 0; i < 3; ++i) {
        int d = threadIdx.x + i * 256;
        float y = (x[i] - mean) * rstd * ln_s[d] + ln_b[d];
        yv[i] = y;
        if constexpr (!FEATS) {
            h[(size_t)tok * HH + d] = y;
            rowbuf[d] = y;
        }
    }
    if constexpr (!FEATS) {
        __syncthreads();
        if (threadIdx.x < 96) write_h_planes(rowbuf, tok, dh, dl, threadIdx.x);
    } else {
        float pt[5] = {0.f, 0.f, 0.f, 0.f, 0.f};
#pragma unroll
        for (int i = 0; i < 3; ++i) {
            int d = threadIdx.x + i * 256;
#pragma unroll
            for (int t = 0; t < 5; ++t) pt[t] += yv[i] * Wt[d * 5 + t];
        }
#pragma unroll
        for (int t = 0; t < 5; ++t)
            for (int o = 32; o; o >>= 1) pt[t] += __shfl_down(pt[t], o);
        __shared__ float fred[4][5];
        if ((threadIdx.x & 63) == 0)
#pragma unroll
            for (int t = 0; t < 5; ++t) fred[wid][t] = pt[t];
        __syncthreads();
        if (threadIdx.x < 5) {
            float fs = fred[0][threadIdx.x] + fred[1][threadIdx.x]
                     + fred[2][threadIdx.x] + fred[3][threadIdx.x] + bt[threadIdx.x];
            feats[tok * 5 + threadIdx.x] = fs;
        }
    }
}

// ---------------- weight conversion: f32 [K][N] -> tiled/swizzled f16 hi/lo planes ----------------
// ALL=1: one launch covers all 12 layers (blockIdx.x = l*3456 + b).
template<int ALL>
__global__ __launch_bounds__(256) void wconv_kernel(
    const float* __restrict__ Wqkv, const float* __restrict__ Wo,
    const float* __restrict__ W1, const float* __restrict__ W2,
    _Float16* __restrict__ qh, _Float16* __restrict__ ql,
    _Float16* __restrict__ oh, _Float16* __restrict__ ol,
    _Float16* __restrict__ f1h, _Float16* __restrict__ f1l,
    _Float16* __restrict__ f2h, _Float16* __restrict__ f2l)
{
    int bb = blockIdx.x;
    int l = ALL ? bb / 3456 : 0;
    int b = ALL ? bb % 3456 : bb;
    const float* src; _Float16 *dh, *dl; int N, kTi, idx;
    if (b < 864)       { idx = b;        src = Wqkv + (size_t)l * 768 * 2304; dh = qh  + (size_t)l * LQS; dl = ql  + (size_t)l * LQS; N = 2304; kTi = 24; }
    else if (b < 1152) { idx = b - 864;  src = Wo   + (size_t)l * 768 * 768;  dh = oh  + (size_t)l * LOS; dl = ol  + (size_t)l * LOS; N = 768;  kTi = 24; }
    else if (b < 2304) { idx = b - 1152; src = W1   + (size_t)l * 768 * 3072; dh = f1h + (size_t)l * L1S; dl = f1l + (size_t)l * L1S; N = 3072; kTi = 24; }
    else               { idx = b - 2304; src = W2   + (size_t)l * 3072 * 768; dh = f2h + (size_t)l * L2S; dl = f2l + (size_t)l * L2S; N = 768;  kTi = 96; }
    int nb = idx / kTi, kb = idx % kTi;

    __shared__ float tile[32][65];
    const float* s0 = src + (size_t)(kb * 32) * N + nb * 64;
#pragma unroll
    for (int i = 0; i < 8; ++i) {
        int q = threadIdx.x + i * 256;
        int kk = q >> 6, n = q & 63;
        tile[kk][n] = s0[(size_t)kk * N + n];
    }
    __syncthreads();
    int p = threadIdx.x;
    int n = p >> 2, koct = (p & 3) ^ (n & 3);
    f16x8 vh, vl;
#pragma unroll
    for (int j = 0; j < 8; ++j) {
        float x = tile[koct * 8 + j][n];
        _Float16 hi = (_Float16)x;
        vh[j] = hi;
        vl[j] = (_Float16)((x - (float)hi) * 4096.f);
    }
    size_t tb = (size_t)idx * 2048;
    *(f16x8*)(dh + tb + (size_t)p * 8) = vh;
    *(f16x8*)(dl + tb + (size_t)p * 8) = vl;
}

// ---------------- split-f16 MFMA GEMM, 128x128 tile ----------------
// MODE 0: normal: A=act 128x32 tiles, B=2 weight 64x32 tiles -> fp32 split-K partials.
// MODE 2: transposed QKV: A=2 weight tiles (M=2304), B=act tile (N=tok) -> Q/K images + V^T.
// MODE 3: transposed FF1: bias+gelu -> FF2 A-planes.
// 4 waves (2m x 2n), wave-tile 64x64 (4x4 frags), 48 MFMA/k-step/wave.
// LDS/buf: [A hi 4096 | A lo 4096 | B hi 4096 | B lo 4096] halves = 32 KB; dbuf 64 KB.
template<int MODE>
__global__ __launch_bounds__(256, 2) void mfma_gemm(
    const _Float16* __restrict__ Ah, const _Float16* __restrict__ Al,
    const _Float16* __restrict__ Bh, const _Float16* __restrict__ Bl,
    const float* __restrict__ bias, float* __restrict__ outF,
    _Float16* __restrict__ o1h, _Float16* __restrict__ o1l,
    _Float16* __restrict__ o2h, _Float16* __restrict__ o2l,
    int N, int kTi, int kpz)
{
    constexpr bool TRANS = (MODE >= 2);
    __shared__ _Float16 lds[2][16384];
    int tid = threadIdx.x, lane = tid & 63, w = tid >> 6;
    int wm = w >> 1, wn = w & 1;
    int mb = blockIdx.y, nb = blockIdx.x;
    int ktBeg = TRANS ? 0 : blockIdx.z * kpz;
    int ktEnd = TRANS ? kTi : ktBeg + kpz;

    f32x4 acch[4][4], accc[4][4];
#pragma unroll
    for (int i = 0; i < 4; ++i)
#pragma unroll
        for (int j = 0; j < 4; ++j) { acch[i][j] = (f32x4)0.f; accc[i][j] = (f32x4)0.f; }

    auto stage = [&](int buf, int kt) {
#pragma unroll
        for (int j = 0; j < 8; ++j) {
            int i = w * 8 + j;
            const _Float16* src;
            if constexpr (!TRANS) {
                if (i < 8)       src = Ah + (size_t)mb * kTi * 4096 + (size_t)kt * 4096 + i * 512;
                else if (i < 16) src = Al + (size_t)mb * kTi * 4096 + (size_t)kt * 4096 + (i - 8) * 512;
                else if (i < 24) { int t = (i - 16) >> 2;
                                   src = Bh + (size_t)(nb * 2 + t) * kTi * 2048 + (size_t)kt * 2048 + ((i - 16) & 3) * 512; }
                else             { int t = (i - 24) >> 2;
                                   src = Bl + (size_t)(nb * 2 + t) * kTi * 2048 + (size_t)kt * 2048 + ((i - 24) & 3) * 512; }
            } else {
                if (i < 8)       { int t = i >> 2;
                                   src = Ah + (size_t)(2 * mb + t) * kTi * 2048 + (size_t)kt * 2048 + (i & 3) * 512; }
                else if (i < 16) { int t = (i - 8) >> 2;
                                   src = Al + (size_t)(2 * mb + t) * kTi * 2048 + (size_t)kt * 2048 + ((i - 8) & 3) * 512; }
                else if (i < 24) src = Bh + (size_t)nb * kTi * 4096 + (size_t)kt * 4096 + (i - 16) * 512;
                else             src = Bl + (size_t)nb * kTi * 4096 + (size_t)kt * 4096 + (i - 24) * 512;
            }
            gl_lds16(src + lane * 8, &lds[buf][i * 512]);
        }
    };

    stage(0, ktBeg);
    __syncthreads();
    int buf = 0;
    int lm = lane & 15, lk = lane >> 4;
    for (int kt = ktBeg; kt < ktEnd; ++kt) {
        if (kt + 1 < ktEnd) stage(buf ^ 1, kt + 1);
        const char* lb = (const char*)&lds[buf][0];
        f16x8 ahf[4], alf[4], bhf[4], blf[4];
#pragma unroll
        for (int mi = 0; mi < 4; ++mi) {
            int row = wm * 64 + mi * 16 + lm;
            int off = (row * 64 + lk * 16) ^ ((row & 3) << 4);
            ahf[mi] = *(const f16x8*)(lb + off);
            alf[mi] = *(const f16x8*)(lb + 8192 + off);
        }
#pragma unroll
        for (int ni = 0; ni < 4; ++ni) {
            int offb;
            if constexpr (!TRANS) {
                int nr = ni * 16 + lm;
                offb = wn * 4096 + ((nr * 64 + lk * 16) ^ ((nr & 3) << 4));
            } else {
                int nr2 = wn * 64 + ni * 16 + lm;
                offb = (nr2 * 64 + lk * 16) ^ ((nr2 & 3) << 4);
            }
            bhf[ni] = *(const f16x8*)(lb + 16384 + offb);
            blf[ni] = *(const f16x8*)(lb + 24576 + offb);
        }
#pragma unroll
        for (int mi = 0; mi < 4; ++mi)
#pragma unroll
            for (int ni = 0; ni < 4; ++ni) {
                acch[mi][ni] = __builtin_amdgcn_mfma_f32_16x16x32_f16(ahf[mi], bhf[ni], acch[mi][ni], 0, 0, 0);
                accc[mi][ni] = __builtin_amdgcn_mfma_f32_16x16x32_f16(ahf[mi], blf[ni], accc[mi][ni], 0, 0, 0);
                accc[mi][ni] = __builtin_amdgcn_mfma_f32_16x16x32_f16(alf[mi], bhf[ni], accc[mi][ni], 0, 0, 0);
            }
        __syncthreads();
        buf ^= 1;
    }

    const float inv = 1.0f / 4096.0f;
    if constexpr (MODE == 0) {
        float* Cz = outF + (size_t)blockIdx.z * 1024 * N;
#pragma unroll
        for (int mi = 0; mi < 4; ++mi)
#pragma unroll
            for (int ni = 0; ni < 4; ++ni) {
                int col = nb * 128 + wn * 64 + ni * 16 + lm;
                int r0 = mb * 128 + wm * 64 + mi * 16 + lk * 4;
#pragma unroll
                for (int j = 0; j < 4; ++j)
                    Cz[(size_t)(r0 + j) * N + col] = acch[mi][ni][j] + accc[mi][ni][j] * inv;
            }
    } else if constexpr (MODE == 2) {
        int region = mb / 6;   // 0=Q 1=K 2=V
#pragma unroll
        for (int mi = 0; mi < 4; ++mi)
#pragma unroll
            for (int ni = 0; ni < 4; ++ni) {
                int n = mb * 128 + wm * 64 + mi * 16 + lk * 4;
                int tok = nb * 128 + wn * 64 + ni * 16 + lm;
                float4 bv = *(const float4*)(bias + n);
                float v[4];
#pragma unroll
                for (int j = 0; j < 4; ++j)
                    v[j] = acch[mi][ni][j] + accc[mi][ni][j] * inv + (&bv.x)[j];
                int b = tok >> 7, q = tok & 127;
                if (region < 2) {
                    int hh2 = (n >> 6) % 12, d = n & 63;
                    size_t img = (size_t)(b * 12 + hh2);
                    _Float16* dsth = (region == 0) ? o1h : o2h;
                    _Float16* dstl = (region == 0) ? o1l : o2l;
                    int byteo = q * 128 + ((d * 2) ^ ((q & 7) << 4));
                    f16x4 hi, lo;
#pragma unroll
                    for (int j = 0; j < 4; ++j) {
                        _Float16 hv = (_Float16)v[j];
                        hi[j] = hv; lo[j] = (_Float16)((v[j] - (float)hv) * 4096.f);
                    }
                    *(f16x4*)((char*)dsth + img * 16384 + byteo) = hi;
                    *(f16x4*)((char*)dstl + img * 16384 + byteo) = lo;
                } else {
                    int hh2 = (n - 1536) >> 6, d = n & 63;
                    float* vdst = outF + (size_t)(b * 12 + hh2) * 8192;
#pragma unroll
                    for (int j = 0; j < 4; ++j)
                        vdst[(size_t)(d + j) * 128 + q] = v[j];
                }
            }
    } else { // MODE 3: FF1 transposed, bias+gelu -> gA planes
#pragma unroll
        for (int mi = 0; mi < 4; ++mi)
#pragma unroll
            for (int ni = 0; ni < 4; ++ni) {
                int n = mb * 128 + wm * 64 + mi * 16 + lk * 4;
                int tok = nb * 128 + wn * 64 + ni * 16 + lm;
                float4 bv = *(const float4*)(bias + n);
                int mbt = tok >> 7, rowm = tok & 127;
                int kb = n >> 5, koct = (n >> 3) & 3, half = (n >> 2) & 1;
                size_t eo = ((size_t)(mbt * 96 + kb)) * 4096
                          + (size_t)(rowm * 4 + (koct ^ (rowm & 3))) * 8 + half * 4;
                f16x4 hi, lo;
#pragma unroll
                for (int j = 0; j < 4; ++j) {
                    float x = gelu_f(acch[mi][ni][j] + accc[mi][ni][j] * inv + (&bv.x)[j]);
                    _Float16 hv = (_Float16)x;
                    hi[j] = hv; lo[j] = (_Float16)((x - (float)hv) * 4096.f);
                }
                *(f16x4*)(o1h + eo) = hi;
                *(f16x4*)(o1l + eo) = lo;
            }
    }
}

// ---------------- fused MFMA attention, one block per (b,h,q-half) ----------------
// LDS = exactly 80 KB; no waves/EU floor (avoid VGPR cap -> spills).
__global__ __launch_bounds__(256, 1) void attn_mfma(
    const _Float16* __restrict__ Qp_h, const _Float16* __restrict__ Qp_l,
    const _Float16* __restrict__ Kp_h, const _Float16* __restrict__ Kp_l,
    const float* __restrict__ vT, const int* __restrict__ mask,
    _Float16* __restrict__ cA_h, _Float16* __restrict__ cA_l)
{
    __shared__ __align__(16) char sm[81920];
    char* Kh  = sm;             char* Klo = sm + 16384;
    char* Qh  = sm + 32768;     char* Qlo = sm + 40960;
    char* Ph  = sm;             char* Plo = sm + 16384;   // reuse K region after QK^T
    char* Vth = sm + 49152;     char* Vtl = sm + 65536;

    int bx = blockIdx.x;               // 0..191
    int bh = bx >> 1, qh2 = bx & 1;
    int b = bh / 12, h = bh % 12;
    int q0 = qh2 * 64;
    int tid = threadIdx.x, lane = tid & 63, wv = tid >> 6;
    int lm = lane & 15, g = lane >> 4;
    int qr = wv * 16 + lm;             // local q row 0..63
    const float inv = 1.0f / 4096.0f;

    {
        const _Float16* Ksh = Kp_h + (size_t)bh * 8192;
        const _Float16* Ksl = Kp_l + (size_t)bh * 8192;
        const _Float16* Qsh = Qp_h + (size_t)bh * 8192 + (size_t)q0 * 64;
        const _Float16* Qsl = Qp_l + (size_t)bh * 8192 + (size_t)q0 * 64;
#pragma unroll
        for (int i = 0; i < 4; ++i) {
            gl_lds16(Ksh + (size_t)(i * 256 + tid) * 8, (_Float16*)(Kh  + (i * 256 + tid) * 16));
            gl_lds16(Ksl + (size_t)(i * 256 + tid) * 8, (_Float16*)(Klo + (i * 256 + tid) * 16));
        }
#pragma unroll
        for (int i = 0; i < 2; ++i) {
            gl_lds16(Qsh + (size_t)(i * 256 + tid) * 8, (_Float16*)(Qh  + (i * 256 + tid) * 16));
            gl_lds16(Qsl + (size_t)(i * 256 + tid) * 8, (_Float16*)(Qlo + (i * 256 + tid) * 16));
        }
    }
    // mask bias -> registers (128 ints, L1-resident)
    float kb_[8][4];
    {
        const int* mrow = mask + b * 128;
#pragma unroll
        for (int mf = 0; mf < 8; ++mf) {
            int4 mv = *(const int4*)(mrow + mf * 16 + g * 4);
            kb_[mf][0] = (1.f - (float)mv.x) * -10000.f;
            kb_[mf][1] = (1.f - (float)mv.y) * -10000.f;
            kb_[mf][2] = (1.f - (float)mv.z) * -10000.f;
            kb_[mf][3] = (1.f - (float)mv.w) * -10000.f;
        }
    }
    __syncthreads();

    // ---- QK^T: S^T[k=128][q=64], each wave owns 16 q-cols
    f32x4 ah[8], ac[8];
#pragma unroll
    for (int i = 0; i < 8; ++i) { ah[i] = (f32x4)0.f; ac[i] = (f32x4)0.f; }
    __builtin_amdgcn_s_setprio(1);
#pragma unroll
    for (int ks = 0; ks < 2; ++ks) {
        int qoff = qr * 128 + ((ks * 64 + g * 16) ^ ((qr & 7) << 4));
        f16x8 q_h = *(const f16x8*)(Qh + qoff);
        f16x8 q_l = *(const f16x8*)(Qlo + qoff);
#pragma unroll
        for (int mf = 0; mf < 8; ++mf) {
            int kt = mf * 16 + lm;
            int koff = kt * 128 + ((ks * 64 + g * 16) ^ ((kt & 7) << 4));
            f16x8 k_h = *(const f16x8*)(Kh + koff);
            f16x8 k_l = *(const f16x8*)(Klo + koff);
            ah[mf] = __builtin_amdgcn_mfma_f32_16x16x32_f16(k_h, q_h, ah[mf], 0, 0, 0);
            ac[mf] = __builtin_amdgcn_mfma_f32_16x16x32_f16(k_h, q_l, ac[mf], 0, 0, 0);
            ac[mf] = __builtin_amdgcn_mfma_f32_16x16x32_f16(k_l, q_h, ac[mf], 0, 0, 0);
        }
    }
    __builtin_amdgcn_s_setprio(0);

    float pv_[8][4];
    float mx = -1e30f;
#pragma unroll
    for (int mf = 0; mf < 8; ++mf)
#pragma unroll
        for (int jj = 0; jj < 4; ++jj) {
            float s = (ah[mf][jj] + ac[mf][jj] * inv) * 0.125f + kb_[mf][jj];
            pv_[mf][jj] = s;
            mx = fmaxf(mx, s);
        }
    mx = fmaxf(mx, __shfl_xor(mx, 16));
    mx = fmaxf(mx, __shfl_xor(mx, 32));
    float sum = 0.f;
#pragma unroll
    for (int mf = 0; mf < 8; ++mf)
#pragma unroll
        for (int jj = 0; jj < 4; ++jj) {
            float e = expf(pv_[mf][jj] - mx);
            pv_[mf][jj] = e;
            sum += e;
        }
    sum += __shfl_xor(sum, 16);
    sum += __shfl_xor(sum, 32);
    float rs = 1.f / sum;
    __syncthreads();   // all waves done reading Q/K before P overwrites

    // write P planes [qr][128k] f16 hi/lo, swizzled
#pragma unroll
    for (int mf = 0; mf < 8; ++mf) {
        f16x4 hi, lo;
#pragma unroll
        for (int jj = 0; jj < 4; ++jj) {
            float p = pv_[mf][jj] * rs;
            _Float16 hv = (_Float16)p;
            hi[jj] = hv; lo[jj] = (_Float16)((p - (float)hv) * 4096.f);
        }
        int byteo = qr * 256 + ((mf * 32 + g * 8) ^ ((qr & 7) << 4));
        *(f16x4*)(Ph + byteo) = hi;
        *(f16x4*)(Plo + byteo) = lo;
    }
    // stage V^T planes [d][128tok] from fp32 vT
    {
        int d = tid >> 2, tb = (tid & 3) * 32;
        const float* vsrc = vT + (size_t)bh * 8192 + (size_t)d * 128 + tb;
#pragma unroll
        for (int i = 0; i < 8; ++i) {
            float4 v = *(const float4*)(vsrc + i * 4);
            f16x4 hi, lo;
#pragma unroll
            for (int jj = 0; jj < 4; ++jj) {
                float x = (&v.x)[jj];
                _Float16 hv = (_Float16)x;
                hi[jj] = hv; lo[jj] = (_Float16)((x - (float)hv) * 4096.f);
            }
            int byteo = d * 256 + (((tb + i * 4) * 2) ^ ((d & 7) << 4));
            *(f16x4*)(Vth + byteo) = hi;
            *(f16x4*)(Vtl + byteo) = lo;
        }
    }
    __syncthreads();

    // ---- PV: ctx^T[d=64][q=64] = V^T @ P^T
    f32x4 ch[4], cc[4];
#pragma unroll
    for (int i = 0; i < 4; ++i) { ch[i] = (f32x4)0.f; cc[i] = (f32x4)0.f; }
    __builtin_amdgcn_s_setprio(1);
#pragma unroll
    for (int ks = 0; ks < 4; ++ks) {
        int poff = qr * 256 + ((ks * 64 + g * 16) ^ ((qr & 7) << 4));
        f16x8 p_h = *(const f16x8*)(Ph + poff);
        f16x8 p_l = *(const f16x8*)(Plo + poff);
#pragma unroll
        for (int mf = 0; mf < 4; ++mf) {
            int d = mf * 16 + lm;
            int voff = d * 256 + ((ks * 64 + g * 16) ^ ((d & 7) << 4));
            f16x8 vh = *(const f16x8*)(Vth + voff);
            f16x8 vl = *(const f16x8*)(Vtl + voff);
            ch[mf] = __builtin_amdgcn_mfma_f32_16x16x32_f16(vh, p_h, ch[mf], 0, 0, 0);
            cc[mf] = __builtin_amdgcn_mfma_f32_16x16x32_f16(vh, p_l, cc[mf], 0, 0, 0);
            cc[mf] = __builtin_amdgcn_mfma_f32_16x16x32_f16(vl, p_h, cc[mf], 0, 0, 0);
        }
    }
    __builtin_amdgcn_s_setprio(0);

    // ---- epilogue: emit cA planes
    int q = q0 + qr;
#pragma unroll
    for (int mf = 0; mf < 4; ++mf) {
        int d0 = mf * 16 + g * 4;
        f16x4 hi, lo;
#pragma unroll
        for (int jj = 0; jj < 4; ++jj) {
            float x = ch[mf][jj] + cc[mf][jj] * inv;
            _Float16 hv = (_Float16)x;
            hi[jj] = hv; lo[jj] = (_Float16)((x - (float)hv) * 4096.f);
        }
        int kb = h * 2 + (d0 >> 5), koct = (d0 >> 3) & 3, half = (d0 >> 2) & 1;
        size_t eo = ((size_t)(b * 24 + kb)) * 4096
                  + (size_t)(q * 4 + (koct ^ (q & 3))) * 8 + half * 4;
        *(f16x4*)(cA_h + eo) = hi;
        *(f16x4*)(cA_l + eo) = lo;
    }
}

// ---------------- Viterbi ----------------
__global__ __launch_bounds__(64) void viterbi_kernel(
    const float* __restrict__ feats, const float* __restrict__ trans,
    float* __restrict__ out)
{
    __shared__ float tr[KT][KT];
    __shared__ unsigned char psi[TT - 1][BB][KT];
    int tid = threadIdx.x;
    if (tid < KT * KT) tr[tid / KT][tid % KT] = trans[tid];
    __syncthreads();
    if (tid < BB) {
        int b = tid;
        float ld[KT];
#pragma unroll
        for (int k = 0; k < KT; ++k) ld[k] = (k == START_TAG) ? 0.f : -10000.f;
        for (int t = 1; t < TT; ++t) {
            float nld[KT];
#pragma unroll
            for (int to = 0; to < KT; ++to) {
                float best = tr[to][0] + ld[0];
                int arg = 0;
#pragma unroll
                for (int fr = 1; fr < KT; ++fr) {
                    float v = tr[to][fr] + ld[fr];
                    if (v > best) { best = v; arg = fr; }
                }
                psi[t - 1][b][to] = (unsigned char)arg;
                nld[to] = best + feats[(size_t)(b * TT + t) * KT + to];
            }
#pragma unroll
            for (int k = 0; k < KT; ++k) ld[k] = nld[k];
        }
        float sc = ld[0]; int last = 0;
#pragma unroll
        for (int k = 1; k < KT; ++k) if (ld[k] > sc) { sc = ld[k]; last = k; }
        out[b] = sc;
        int p = last;
        out[BB + b * TT + (TT - 1)] = (float)last;
        for (int t = TT - 2; t >= 0; --t) {
            p = psi[t][b][p];
            out[BB + b * TT + t] = (float)p;
        }
    }
}

extern "C" void kernel_launch(void* const* d_in, const int* in_sizes, int n_in,
                              void* d_out, int out_size, void* d_ws, size_t ws_size,
                              hipStream_t stream) {
    const int*   sentence = (const int*)d_in[0];
    const int*   mask     = (const int*)d_in[1];
    const float* word_emb = (const float*)d_in[2];
    const float* pos_emb  = (const float*)d_in[3];
    const float* type_emb = (const float*)d_in[4];
    const float* emb_ln_s = (const float*)d_in[5];
    const float* emb_ln_b = (const float*)d_in[6];
    const float* Wqkv     = (const float*)d_in[7];
    const float* bqkv     = (const float*)d_in[8];
    const float* Wo       = (const float*)d_in[9];
    const float* bo       = (const float*)d_in[10];
    const float* ln1_s    = (const float*)d_in[11];
    const float* ln1_b    = (const float*)d_in[12];
    const float* W1       = (const float*)d_in[13];
    const float* b1       = (const float*)d_in[14];
    const float* W2       = (const float*)d_in[15];
    const float* b2       = (const float*)d_in[16];
    const float* ln2_s    = (const float*)d_in[17];
    const float* ln2_b    = (const float*)d_in[18];
    const float* Wt       = (const float*)d_in[19];
    const float* bt       = (const float*)d_in[20];
    const float* trans    = (const float*)d_in[21];

    char* base = (char*)d_ws;
    size_t off = 0;
    auto alloc = [&](size_t bytes) { void* p = base + off; off += (bytes + 255) & ~(size_t)255; return p; };

    // all-layer planes: 339.74 MB; activations: ~44.1 MB; total ~384 MB.
    bool allL = ws_size >= (384ULL << 20);
    int NLL = allL ? 12 : 1;

    _Float16* wq_h = (_Float16*)alloc((size_t)LQS * NLL * 2);
    _Float16* wq_l = (_Float16*)alloc((size_t)LQS * NLL * 2);
    _Float16* wo_h = (_Float16*)alloc((size_t)LOS * NLL * 2);
    _Float16* wo_l = (_Float16*)alloc((size_t)LOS * NLL * 2);
    _Float16* w1_h = (_Float16*)alloc((size_t)L1S * NLL * 2);
    _Float16* w1_l = (_Float16*)alloc((size_t)L1S * NLL * 2);
    _Float16* w2_h = (_Float16*)alloc((size_t)L2S * NLL * 2);
    _Float16* w2_l = (_Float16*)alloc((size_t)L2S * NLL * 2);
    float* h       = (float*)alloc((size_t)MTOK * HH * 4);
    _Float16* hA_h = (_Float16*)alloc((size_t)MTOK * HH * 2);
    _Float16* hA_l = (_Float16*)alloc((size_t)MTOK * HH * 2);
    _Float16* Qp_h = (_Float16*)alloc((size_t)96 * 8192 * 2);
    _Float16* Qp_l = (_Float16*)alloc((size_t)96 * 8192 * 2);
    _Float16* Kp_h = (_Float16*)alloc((size_t)96 * 8192 * 2);
    _Float16* Kp_l = (_Float16*)alloc((size_t)96 * 8192 * 2);
    float* vT      = (float*)alloc((size_t)96 * 8192 * 4);
    _Float16* cA_h = (_Float16*)alloc((size_t)MTOK * HH * 2);
    _Float16* cA_l = (_Float16*)alloc((size_t)MTOK * HH * 2);
    _Float16* gA_h = (_Float16*)alloc((size_t)MTOK * FFI * 2);
    _Float16* gA_l = (_Float16*)alloc((size_t)MTOK * FFI * 2);
    float* parts   = (float*)alloc((size_t)4 * MTOK * HH * 4);
    float* featsb  = (float*)alloc((size_t)MTOK * KT * 4);

    embed_ln_kernel<<<MTOK, 256, 0, stream>>>(sentence, word_emb, pos_emb, type_emb,
                                              emb_ln_s, emb_ln_b, h, hA_h, hA_l);
    if (allL) {
        wconv_kernel<1><<<41472, 256, 0, stream>>>(
            Wqkv, Wo, W1, W2, wq_h, wq_l, wo_h, wo_l, w1_h, w1_l, w2_h, w2_l);
    }
    for (int l = 0; l < LL; ++l) {
        size_t qO  = allL ? (size_t)l * LQS : 0;
        size_t oO  = allL ? (size_t)l * LOS : 0;
        size_t f1O = allL ? (size_t)l * L1S : 0;
        size_t f2O = allL ? (size_t)l * L2S : 0;
        if (!allL) {
            wconv_kernel<0><<<3456, 256, 0, stream>>>(
                Wqkv + (size_t)l * 768 * 2304, Wo + (size_t)l * 768 * 768,
                W1 + (size_t)l * 768 * 3072, W2 + (size_t)l * 3072 * 768,
                wq_h, wq_l, wo_h, wo_l, w1_h, w1_l, w2_h, w2_l);
        }
        // QKV transposed: -> Qp/Kp images + vT   (grid 8x18)
        mfma_gemm<2><<<dim3(8, 18), 256, 0, stream>>>(
            wq_h + qO, wq_l + qO, hA_h, hA_l, bqkv + (size_t)l * 2304, vT,
            Qp_h, Qp_l, Kp_h, Kp_l, 2304, 24, 24);
        attn_mfma<<<192, 256, 0, stream>>>(Qp_h, Qp_l, Kp_h, Kp_l, vT, mask, cA_h, cA_l);
        // Wo: normal, split-K 4 -> parts   (grid 6x8x4)
        mfma_gemm<0><<<dim3(6, 8, 4), 256, 0, stream>>>(
            cA_h, cA_l, wo_h + oO, wo_l + oO, nullptr, parts,
            nullptr, nullptr, nullptr, nullptr, 768, 24, 6);
        add_ln_red_kernel<0><<<MTOK, 256, 0, stream>>>(
            h, parts, bo + (size_t)l * HH, ln1_s + (size_t)l * HH, ln1_b + (size_t)l * HH,
            hA_h, hA_l, nullptr, nullptr, nullptr);
        // FF1 transposed + gelu -> gA planes   (grid 8x24)
        mfma_gemm<3><<<dim3(8, 24), 256, 0, stream>>>(
            w1_h + f1O, w1_l + f1O, hA_h, hA_l, b1 + (size_t)l * FFI, nullptr,
            gA_h, gA_l, nullptr, nullptr, 3072, 24, 24);
        // FF2: normal, split-K 4 -> parts   (grid 6x8x4)
        mfma_gemm<0><<<dim3(6, 8, 4), 256, 0, stream>>>(
            gA_h, gA_l, w2_h + f2O, w2_l + f2O, nullptr, parts,
            nullptr, nullptr, nullptr, nullptr, 768, 96, 24);
        if (l < LL - 1) {
            add_ln_red_kernel<0><<<MTOK, 256, 0, stream>>>(
                h, parts, b2 + (size_t)l * HH, ln2_s + (size_t)l * HH, ln2_b + (size_t)l * HH,
                hA_h, hA_l, nullptr, nullptr, nullptr);
        } else {
            add_ln_red_kernel<1><<<MTOK, 256, 0, stream>>>(
                h, parts, b2 + (size_t)l * HH, ln2_s + (size_t)l * HH, ln2_b + (size_t)l * HH,
                hA_h, hA_l, Wt, bt, featsb);
        }
    }
    viterbi_kernel<<<1, 64, 0, stream>>>(featsb, trans, (float*)d_out);
}

// Round 10
// 1646.364 us; speedup vs baseline: 1.0976x; 1.0976x over previous
//
#include <hip/hip_runtime.h>
#include <cstdint>
#include <cstddef>

#define BB 8
#define TT 128
#define LL 12
#define HH 768
#define NHH 12
#define DHH 64
#define FFI 3072
#define KT 5
#define START_TAG 3
#define MTOK (BB*TT)   // 1024

// per-layer plane strides (elements)
#define LQS 1769472u   // 768*2304
#define LOS 589824u    // 768*768
#define L1S 2359296u   // 768*3072
#define L2S 2359296u   // 3072*768

typedef _Float16 f16x8 __attribute__((ext_vector_type(8)));
typedef _Float16 f16x4 __attribute__((ext_vector_type(4)));
typedef float f32x4 __attribute__((ext_vector_type(4)));

__device__ __forceinline__ void gl_lds16(const _Float16* g, _Float16* l) {
    __builtin_amdgcn_global_load_lds(
        (const __attribute__((address_space(1))) unsigned int*)g,
        (__attribute__((address_space(3))) unsigned int*)l, 16, 0, 0);
}

__device__ __forceinline__ float gelu_f(float x) {
    float c = 0.7978845608028654f * (x + 0.044715f * x * x * x);
    return 0.5f * x * (1.f + tanhf(c));
}

// write one 8-elem chunk of a normalized row into A-plane tiles (K=768, kTiles=24)
__device__ __forceinline__ void write_h_planes(const float* rowbuf, int tok,
                                               _Float16* dh, _Float16* dl, int c) {
    int kb = c >> 2;
    int rowm = tok & 127, mb = tok >> 7;
    int koct = c & 3;
    int p = rowm * 4 + (koct ^ (rowm & 3));
    size_t tb = ((size_t)(mb * 24 + kb)) * 4096;
    f16x8 vh, vl;
#pragma unroll
    for (int j = 0; j < 8; ++j) {
        float x = rowbuf[c * 8 + j];
        _Float16 hi = (_Float16)x;
        vh[j] = hi;
        vl[j] = (_Float16)((x - (float)hi) * 4096.f);
    }
    *(f16x8*)(dh + tb + (size_t)p * 8) = vh;
    *(f16x8*)(dl + tb + (size_t)p * 8) = vl;
}

// ---------------- embedding + LN (+A-plane emit) ----------------
__global__ __launch_bounds__(256) void embed_ln_kernel(
    const int* __restrict__ sentence,
    const float* __restrict__ word_emb,
    const float* __restrict__ pos_emb,
    const float* __restrict__ type_emb,
    const float* __restrict__ ln_s,
    const float* __restrict__ ln_b,
    float* __restrict__ h,
    _Float16* __restrict__ dh, _Float16* __restrict__ dl)
{
    int tok = blockIdx.x;
    int t = tok % TT;
    int id = sentence[tok];
    const float* we = word_emb + (size_t)id * HH;
    const float* pe = pos_emb + (size_t)t * HH;

    __shared__ float rowbuf[HH];
    __shared__ float rs_[4], rss_[4];
    float x[3];
    float s = 0.f, ss = 0.f;
#pragma unroll
    for (int i = 0; i < 3; ++i) {
        int d = threadIdx.x + i * 256;
        float v = we[d] + pe[d] + type_emb[d];
        x[i] = v; s += v; ss += v * v;
    }
    for (int o = 32; o; o >>= 1) { s += __shfl_down(s, o); ss += __shfl_down(ss, o); }
    int wid = threadIdx.x >> 6;
    if ((threadIdx.x & 63) == 0) { rs_[wid] = s; rss_[wid] = ss; }
    __syncthreads();
    s = rs_[0] + rs_[1] + rs_[2] + rs_[3];
    ss = rss_[0] + rss_[1] + rss_[2] + rss_[3];
    float mean = s * (1.f / HH);
    float var = ss * (1.f / HH) - mean * mean;
    float rstd = rsqrtf(var + 1e-12f);
#pragma unroll
    for (int i = 0; i < 3; ++i) {
        int d = threadIdx.x + i * 256;
        float y = (x[i] - mean) * rstd * ln_s[d] + ln_b[d];
        h[(size_t)tok * HH + d] = y;
        rowbuf[d] = y;
    }
    __syncthreads();
    if (threadIdx.x < 96) write_h_planes(rowbuf, tok, dh, dl, threadIdx.x);
}

// ---------------- split-K reduce + bias + residual + LN (+A-plane emit OR feats) ----------------
template<int FEATS>
__global__ __launch_bounds__(256) void add_ln_red_kernel(
    float* __restrict__ h, const float* __restrict__ parts,
    const float* __restrict__ bias,
    const float* __restrict__ ln_s, const float* __restrict__ ln_b,
    _Float16* __restrict__ dh, _Float16* __restrict__ dl,
    const float* __restrict__ Wt, const float* __restrict__ bt,
    float* __restrict__ feats)
{
    int tok = blockIdx.x;
    __shared__ float rowbuf[HH];
    __shared__ float rs_[4], rss_[4];
    float x[3];
    float s = 0.f, ss = 0.f;
#pragma unroll
    for (int i = 0; i < 3; ++i) {
        int d = threadIdx.x + i * 256;
        size_t idx = (size_t)tok * HH + d;
        float delta = parts[idx] + parts[idx + (size_t)MTOK * HH]
                    + parts[idx + 2 * (size_t)MTOK * HH] + parts[idx + 3 * (size_t)MTOK * HH]
                    + bias[d];
        float v = h[idx] + delta;
        x[i] = v; s += v; ss += v * v;
    }
    for (int o = 32; o; o >>= 1) { s += __shfl_down(s, o); ss += __shfl_down(ss, o); }
    int wid = threadIdx.x >> 6;
    if ((threadIdx.x & 63) == 0) { rs_[wid] = s; rss_[wid] = ss; }
    __syncthreads();
    s = rs_[0] + rs_[1] + rs_[2] + rs_[3];
    ss = rss_[0] + rss_[1] + rss_[2] + rss_[3];
    float mean = s * (1.f / HH);
    float var = ss * (1.f / HH) - mean * mean;
    float rstd = rsqrtf(var + 1e-12f);
    float yv[3];
#pragma unroll
    for (int i = 0; i < 3; ++i) {
        int d = threadIdx.x + i * 256;
        float y = (x[i] - mean) * rstd * ln_s[d] + ln_b[d];
        yv[i] = y;
        if constexpr (!FEATS) {
            h[(size_t)tok * HH + d] = y;
            rowbuf[d] = y;
        }
    }
    if constexpr (!FEATS) {
        __syncthreads();
        if (threadIdx.x < 96) write_h_planes(rowbuf, tok, dh, dl, threadIdx.x);
    } else {
        float pt[5] = {0.f, 0.f, 0.f, 0.f, 0.f};
#pragma unroll
        for (int i = 0; i < 3; ++i) {
            int d = threadIdx.x + i * 256;
#pragma unroll
            for (int t = 0; t < 5; ++t) pt[t] += yv[i] * Wt[d * 5 + t];
        }
#pragma unroll
        for (int t = 0; t < 5; ++t)
            for (int o = 32; o; o >>= 1) pt[t] += __shfl_down(pt[t], o);
        __shared__ float fred[4][5];
        if ((threadIdx.x & 63) == 0)
#pragma unroll
            for (int t = 0; t < 5; ++t) fred[wid][t] = pt[t];
        __syncthreads();
        if (threadIdx.x < 5) {
            float fs = fred[0][threadIdx.x] + fred[1][threadIdx.x]
                     + fred[2][threadIdx.x] + fred[3][threadIdx.x] + bt[threadIdx.x];
            feats[tok * 5 + threadIdx.x] = fs;
        }
    }
}

// ---------------- weight conversion: f32 [K][N] -> tiled/swizzled f16 hi/lo planes ----------------
// ALL=1: one launch covers all 12 layers (blockIdx.x = l*3456 + b).
template<int ALL>
__global__ __launch_bounds__(256) void wconv_kernel(
    const float* __restrict__ Wqkv, const float* __restrict__ Wo,
    const float* __restrict__ W1, const float* __restrict__ W2,
    _Float16* __restrict__ qh, _Float16* __restrict__ ql,
    _Float16* __restrict__ oh, _Float16* __restrict__ ol,
    _Float16* __restrict__ f1h, _Float16* __restrict__ f1l,
    _Float16* __restrict__ f2h, _Float16* __restrict__ f2l)
{
    int bb = blockIdx.x;
    int l = ALL ? bb / 3456 : 0;
    int b = ALL ? bb % 3456 : bb;
    const float* src; _Float16 *dh, *dl; int N, kTi, idx;
    if (b < 864)       { idx = b;        src = Wqkv + (size_t)l * 768 * 2304; dh = qh  + (size_t)l * LQS; dl = ql  + (size_t)l * LQS; N = 2304; kTi = 24; }
    else if (b < 1152) { idx = b - 864;  src = Wo   + (size_t)l * 768 * 768;  dh = oh  + (size_t)l * LOS; dl = ol  + (size_t)l * LOS; N = 768;  kTi = 24; }
    else if (b < 2304) { idx = b - 1152; src = W1   + (size_t)l * 768 * 3072; dh = f1h + (size_t)l * L1S; dl = f1l + (size_t)l * L1S; N = 3072; kTi = 24; }
    else               { idx = b - 2304; src = W2   + (size_t)l * 3072 * 768; dh = f2h + (size_t)l * L2S; dl = f2l + (size_t)l * L2S; N = 768;  kTi = 96; }
    int nb = idx / kTi, kb = idx % kTi;

    __shared__ float tile[32][65];
    const float* s0 = src + (size_t)(kb * 32) * N + nb * 64;
#pragma unroll
    for (int i = 0; i < 8; ++i) {
        int q = threadIdx.x + i * 256;
        int kk = q >> 6, n = q & 63;
        tile[kk][n] = s0[(size_t)kk * N + n];
    }
    __syncthreads();
    int p = threadIdx.x;
    int n = p >> 2, koct = (p & 3) ^ (n & 3);
    f16x8 vh, vl;
#pragma unroll
    for (int j = 0; j < 8; ++j) {
        float x = tile[koct * 8 + j][n];
        _Float16 hi = (_Float16)x;
        vh[j] = hi;
        vl[j] = (_Float16)((x - (float)hi) * 4096.f);
    }
    size_t tb = (size_t)idx * 2048;
    *(f16x8*)(dh + tb + (size_t)p * 8) = vh;
    *(f16x8*)(dl + tb + (size_t)p * 8) = vl;
}

// ---------------- split-f16 MFMA GEMM (normal + transposed variants) ----------------
// MODE 0: normal: A=act planes [128x32 tiles], B=weight planes [64x32 tiles],
//         out = fp32 split-K partials C[z][1024][N].
// MODE 2: transposed QKV: A=weight planes (M=2304), B=act planes (N=tok).
//         out: Q/K pre-swizzled f16 images (o1*,o2*) + V^T fp32 (outF). bias=bqkv.
// MODE 3: transposed FF1: bias+gelu, writes FF2 A-planes (o1*). bias=b1.
// K-loop: simple single-depth prefetch + __syncthreads (measured best: 1496 vs
// 1516/1543 for hand-pipelined variants — compiler fine-schedules ds_read/MFMA).
// NOTE: no min-waves launch_bounds — caps the allocator and forces spills
// (r8 attn +~100us, r9 gemm +~180us — measured regressions).
template<int MODE>
__global__ __launch_bounds__(256) void mfma_gemm(
    const _Float16* __restrict__ Ah, const _Float16* __restrict__ Al,
    const _Float16* __restrict__ Bh, const _Float16* __restrict__ Bl,
    const float* __restrict__ bias, float* __restrict__ outF,
    _Float16* __restrict__ o1h, _Float16* __restrict__ o1l,
    _Float16* __restrict__ o2h, _Float16* __restrict__ o2l,
    int N, int kTi, int kpz)
{
    constexpr bool TRANS = (MODE >= 2);
    __shared__ _Float16 lds[2][12288];   // A hi 4096 | A lo 4096 | B hi 2048 | B lo 2048
    int tid = threadIdx.x, lane = tid & 63, w = tid >> 6;
    int wm = w >> 1, wn = w & 1;
    int mb = blockIdx.y, nb = blockIdx.x;
    int ktBeg = TRANS ? 0 : blockIdx.z * kpz;
    int ktEnd = TRANS ? kTi : ktBeg + kpz;

    const _Float16 *aTh, *aTl, *bTh, *bTl;
    if constexpr (!TRANS) {
        aTh = Ah + (size_t)mb * kTi * 4096;
        aTl = Al + (size_t)mb * kTi * 4096;
        bTh = Bh + (size_t)nb * kTi * 2048;
        bTl = Bl + (size_t)nb * kTi * 2048;
    } else {
        aTh = Ah + (size_t)(2 * mb) * kTi * 2048;
        aTl = Al + (size_t)(2 * mb) * kTi * 2048;
        bTh = Bh + (size_t)(nb >> 1) * kTi * 4096 + (nb & 1) * 2048;
        bTl = Bl + (size_t)(nb >> 1) * kTi * 4096 + (nb & 1) * 2048;
    }

    f32x4 acch[4][2], accc[4][2];
#pragma unroll
    for (int i = 0; i < 4; ++i)
#pragma unroll
        for (int j = 0; j < 2; ++j) { acch[i][j] = (f32x4)0.f; accc[i][j] = (f32x4)0.f; }

    auto stage = [&](int buf, int kt) {
#pragma unroll
        for (int j = 0; j < 6; ++j) {
            int i = w * 6 + j;
            const _Float16* src;
            if constexpr (!TRANS) {
                if (i < 8)       src = aTh + (size_t)kt * 4096 + i * 512;
                else if (i < 16) src = aTl + (size_t)kt * 4096 + (i - 8) * 512;
                else if (i < 20) src = bTh + (size_t)kt * 2048 + (i - 16) * 512;
                else             src = bTl + (size_t)kt * 2048 + (i - 20) * 512;
            } else {
                if (i < 8)       src = aTh + (size_t)(i >> 2) * kTi * 2048 + (size_t)kt * 2048 + (i & 3) * 512;
                else if (i < 16) src = aTl + (size_t)((i - 8) >> 2) * kTi * 2048 + (size_t)kt * 2048 + ((i - 8) & 3) * 512;
                else if (i < 20) src = bTh + (size_t)kt * 4096 + (i - 16) * 512;
                else             src = bTl + (size_t)kt * 4096 + (i - 20) * 512;
            }
            gl_lds16(src + lane * 8, &lds[buf][i * 512]);
        }
    };

    stage(0, ktBeg);
    __syncthreads();
    int buf = 0;
    int lm = lane & 15, lk = lane >> 4;
    for (int kt = ktBeg; kt < ktEnd; ++kt) {
        if (kt + 1 < ktEnd) stage(buf ^ 1, kt + 1);
        const char* lb = (const char*)&lds[buf][0];
        f16x8 ahf[4], alf[4], bhf[2], blf[2];
#pragma unroll
        for (int mi = 0; mi < 4; ++mi) {
            int row = wm * 64 + mi * 16 + lm;
            int off = (row * 64 + lk * 16) ^ ((row & 3) << 4);
            ahf[mi] = *(const f16x8*)(lb + off);
            alf[mi] = *(const f16x8*)(lb + 8192 + off);
        }
#pragma unroll
        for (int ni = 0; ni < 2; ++ni) {
            int nr = wn * 32 + ni * 16 + lm;
            int off = (nr * 64 + lk * 16) ^ ((nr & 3) << 4);
            bhf[ni] = *(const f16x8*)(lb + 16384 + off);
            blf[ni] = *(const f16x8*)(lb + 20480 + off);
        }
#pragma unroll
        for (int mi = 0; mi < 4; ++mi)
#pragma unroll
            for (int ni = 0; ni < 2; ++ni) {
                acch[mi][ni] = __builtin_amdgcn_mfma_f32_16x16x32_f16(ahf[mi], bhf[ni], acch[mi][ni], 0, 0, 0);
                accc[mi][ni] = __builtin_amdgcn_mfma_f32_16x16x32_f16(ahf[mi], blf[ni], accc[mi][ni], 0, 0, 0);
                accc[mi][ni] = __builtin_amdgcn_mfma_f32_16x16x32_f16(alf[mi], bhf[ni], accc[mi][ni], 0, 0, 0);
            }
        __syncthreads();
        buf ^= 1;
    }

    const float inv = 1.0f / 4096.0f;
    if constexpr (MODE == 0) {
        float* Cz = outF + (size_t)blockIdx.z * 1024 * N;
#pragma unroll
        for (int mi = 0; mi < 4; ++mi)
#pragma unroll
            for (int ni = 0; ni < 2; ++ni) {
                int col = nb * 64 + wn * 32 + ni * 16 + lm;
                int r0 = mb * 128 + wm * 64 + mi * 16 + lk * 4;
#pragma unroll
                for (int j = 0; j < 4; ++j)
                    Cz[(size_t)(r0 + j) * N + col] = acch[mi][ni][j] + accc[mi][ni][j] * inv;
            }
    } else if constexpr (MODE == 2) {
        int region = mb / 6;   // 0=Q 1=K 2=V
#pragma unroll
        for (int mi = 0; mi < 4; ++mi)
#pragma unroll
            for (int ni = 0; ni < 2; ++ni) {
                int n = mb * 128 + wm * 64 + mi * 16 + lk * 4;
                int tok = nb * 64 + wn * 32 + ni * 16 + lm;
                float4 bv = *(const float4*)(bias + n);
                float v[4];
#pragma unroll
                for (int j = 0; j < 4; ++j)
                    v[j] = acch[mi][ni][j] + accc[mi][ni][j] * inv + (&bv.x)[j];
                int b = tok >> 7, q = tok & 127;
                if (region < 2) {
                    int hh2 = (n >> 6) % 12, d = n & 63;
                    size_t img = (size_t)(b * 12 + hh2);
                    _Float16* dsth = (region == 0) ? o1h : o2h;
                    _Float16* dstl = (region == 0) ? o1l : o2l;
                    int byteo = q * 128 + ((d * 2) ^ ((q & 7) << 4));
                    f16x4 hi, lo;
#pragma unroll
                    for (int j = 0; j < 4; ++j) {
                        _Float16 hv = (_Float16)v[j];
                        hi[j] = hv; lo[j] = (_Float16)((v[j] - (float)hv) * 4096.f);
                    }
                    *(f16x4*)((char*)dsth + img * 16384 + byteo) = hi;
                    *(f16x4*)((char*)dstl + img * 16384 + byteo) = lo;
                } else {
                    int hh2 = (n - 1536) >> 6, d = n & 63;
                    float* vdst = outF + (size_t)(b * 12 + hh2) * 8192;
#pragma unroll
                    for (int j = 0; j < 4; ++j)
                        vdst[(size_t)(d + j) * 128 + q] = v[j];
                }
            }
    } else { // MODE 3: FF1 transposed, bias+gelu -> gA planes
#pragma unroll
        for (int mi = 0; mi < 4; ++mi)
#pragma unroll
            for (int ni = 0; ni < 2; ++ni) {
                int n = mb * 128 + wm * 64 + mi * 16 + lk * 4;
                int tok = nb * 64 + wn * 32 + ni * 16 + lm;
                float4 bv = *(const float4*)(bias + n);
                int mbt = tok >> 7, rowm = tok & 127;
                int kb = n >> 5, koct = (n >> 3) & 3, half = (n >> 2) & 1;
                size_t eo = ((size_t)(mbt * 96 + kb)) * 4096
                          + (size_t)(rowm * 4 + (koct ^ (rowm & 3))) * 8 + half * 4;
                f16x4 hi, lo;
#pragma unroll
                for (int j = 0; j < 4; ++j) {
                    float x = gelu_f(acch[mi][ni][j] + accc[mi][ni][j] * inv + (&bv.x)[j]);
                    _Float16 hv = (_Float16)x;
                    hi[j] = hv; lo[j] = (_Float16)((x - (float)hv) * 4096.f);
                }
                *(f16x4*)(o1h + eo) = hi;
                *(f16x4*)(o1l + eo) = lo;
            }
    }
}

// ---------------- fused MFMA attention, one block per (b,h) ----------------
// (measured-best r3 config: 96 blocks, 98816B LDS, no setprio, no min-waves)
__global__ __launch_bounds__(256, 1) void attn_mfma(
    const _Float16* __restrict__ Qp_h, const _Float16* __restrict__ Qp_l,
    const _Float16* __restrict__ Kp_h, const _Float16* __restrict__ Kp_l,
    const float* __restrict__ vT, const int* __restrict__ mask,
    _Float16* __restrict__ cA_h, _Float16* __restrict__ cA_l)
{
    __shared__ __align__(16) char sm[98816];
    char* Kh = sm;            char* Klo = sm + 16384;
    char* Qh = sm + 32768;    char* Qlo = sm + 49152;
    char* Ph = sm;            char* Plo = sm + 32768;    // reuse after barrier
    char* Vth = sm + 65536;   char* Vtl = sm + 81920;
    float* biasf = (float*)(sm + 98304);

    int bx = blockIdx.x; int b = bx / 12, h = bx % 12;
    int tid = threadIdx.x, lane = tid & 63, wv = tid >> 6;
    int lm = lane & 15, g = lane >> 4;
    const float inv = 1.0f / 4096.0f;

    {
        const _Float16* srcs[4] = { Kp_h + (size_t)bx * 8192, Kp_l + (size_t)bx * 8192,
                                    Qp_h + (size_t)bx * 8192, Qp_l + (size_t)bx * 8192 };
        char* dsts[4] = { Kh, Klo, Qh, Qlo };
#pragma unroll
        for (int p = 0; p < 4; ++p)
#pragma unroll
            for (int r = 0; r < 4; ++r) {
                int cbase = r * 256 + wv * 64;
                gl_lds16(srcs[p] + (size_t)(cbase + lane) * 8, (_Float16*)(dsts[p] + (size_t)cbase * 16));
            }
    }
    if (tid < 128) biasf[tid] = (1.f - (float)mask[b * 128 + tid]) * -10000.f;
    __syncthreads();

    // ---- QK^T: S^T[k][q], wave wv owns q-cols [wv*32, wv*32+32)
    f32x4 ah[8][2], ac[8][2];
#pragma unroll
    for (int i = 0; i < 8; ++i)
#pragma unroll
        for (int j = 0; j < 2; ++j) { ah[i][j] = (f32x4)0.f; ac[i][j] = (f32x4)0.f; }
#pragma unroll
    for (int ks = 0; ks < 2; ++ks) {
        f16x8 qf[2][2];
#pragma unroll
        for (int nf = 0; nf < 2; ++nf) {
            int q = wv * 32 + nf * 16 + lm;
            int off = (q * 128 + ks * 64 + g * 16) ^ ((q & 7) << 4);
            qf[nf][0] = *(const f16x8*)(Qh + off);
            qf[nf][1] = *(const f16x8*)(Qlo + off);
        }
#pragma unroll
        for (int mf = 0; mf < 8; ++mf) {
            int kt = mf * 16 + lm;
            int off = (kt * 128 + ks * 64 + g * 16) ^ ((kt & 7) << 4);
            f16x8 kh = *(const f16x8*)(Kh + off);
            f16x8 kl = *(const f16x8*)(Klo + off);
#pragma unroll
            for (int nf = 0; nf < 2; ++nf) {
                ah[mf][nf] = __builtin_amdgcn_mfma_f32_16x16x32_f16(kh, qf[nf][0], ah[mf][nf], 0, 0, 0);
                ac[mf][nf] = __builtin_amdgcn_mfma_f32_16x16x32_f16(kh, qf[nf][1], ac[mf][nf], 0, 0, 0);
                ac[mf][nf] = __builtin_amdgcn_mfma_f32_16x16x32_f16(kl, qf[nf][0], ac[mf][nf], 0, 0, 0);
            }
        }
    }

    float kb_[8][4];
#pragma unroll
    for (int mf = 0; mf < 8; ++mf)
#pragma unroll
        for (int jj = 0; jj < 4; ++jj) kb_[mf][jj] = biasf[mf * 16 + g * 4 + jj];

    float pv_[2][8][4], rs_[2];
#pragma unroll
    for (int nf = 0; nf < 2; ++nf) {
        float mx = -1e30f;
#pragma unroll
        for (int mf = 0; mf < 8; ++mf)
#pragma unroll
            for (int jj = 0; jj < 4; ++jj) {
                float s = (ah[mf][nf][jj] + ac[mf][nf][jj] * inv) * 0.125f + kb_[mf][jj];
                pv_[nf][mf][jj] = s;
                mx = fmaxf(mx, s);
            }
        mx = fmaxf(mx, __shfl_xor(mx, 16));
        mx = fmaxf(mx, __shfl_xor(mx, 32));
        float sum = 0.f;
#pragma unroll
        for (int mf = 0; mf < 8; ++mf)
#pragma unroll
            for (int jj = 0; jj < 4; ++jj) {
                float e = expf(pv_[nf][mf][jj] - mx);
                pv_[nf][mf][jj] = e;
                sum += e;
            }
        sum += __shfl_xor(sum, 16);
        sum += __shfl_xor(sum, 32);
        rs_[nf] = 1.f / sum;
    }
    __syncthreads();   // all waves done reading Q/K

    // write P planes [q][128k] f16 hi/lo, swizzled
#pragma unroll
    for (int nf = 0; nf < 2; ++nf) {
        int q = wv * 32 + nf * 16 + lm;
#pragma unroll
        for (int mf = 0; mf < 8; ++mf) {
            f16x4 hi, lo;
#pragma unroll
            for (int jj = 0; jj < 4; ++jj) {
                float p = pv_[nf][mf][jj] * rs_[nf];
                _Float16 hv = (_Float16)p;
                hi[jj] = hv; lo[jj] = (_Float16)((p - (float)hv) * 4096.f);
            }
            int byteo = (q * 256 + mf * 32 + g * 8) ^ ((q & 7) << 4);
            *(f16x4*)(Ph + byteo) = hi;
            *(f16x4*)(Plo + byteo) = lo;
        }
    }
    // stage V^T planes [d][128tok] from fp32 vT
    {
        int d = tid >> 2, tb = (tid & 3) * 32;
        const float* vsrc = vT + (size_t)bx * 8192 + (size_t)d * 128 + tb;
#pragma unroll
        for (int i = 0; i < 8; ++i) {
            float4 v = *(const float4*)(vsrc + i * 4);
            f16x4 hi, lo;
#pragma unroll
            for (int jj = 0; jj < 4; ++jj) {
                float x = (&v.x)[jj];
                _Float16 hv = (_Float16)x;
                hi[jj] = hv; lo[jj] = (_Float16)((x - (float)hv) * 4096.f);
            }
            int byteo = (d * 256 + (tb + i * 4) * 2) ^ ((d & 7) << 4);
            *(f16x4*)(Vth + byteo) = hi;
            *(f16x4*)(Vtl + byteo) = lo;
        }
    }
    __syncthreads();

    // ---- PV: ctx^T[d][q] = V^T @ P^T
    f32x4 ch[4][2], cc[4][2];
#pragma unroll
    for (int i = 0; i < 4; ++i)
#pragma unroll
        for (int j = 0; j < 2; ++j) { ch[i][j] = (f32x4)0.f; cc[i][j] = (f32x4)0.f; }
#pragma unroll
    for (int ks = 0; ks < 4; ++ks) {
        f16x8 pf[2][2];
#pragma unroll
        for (int nf = 0; nf < 2; ++nf) {
            int q = wv * 32 + nf * 16 + lm;
            int off = (q * 256 + ks * 64 + g * 16) ^ ((q & 7) << 4);
            pf[nf][0] = *(const f16x8*)(Ph + off);
            pf[nf][1] = *(const f16x8*)(Plo + off);
        }
#pragma unroll
        for (int mf = 0; mf < 4; ++mf) {
            int d = mf * 16 + lm;
            int off = (d * 256 + ks * 64 + g * 16) ^ ((d & 7) << 4);
            f16x8 vh = *(const f16x8*)(Vth + off);
            f16x8 vl = *(const f16x8*)(Vtl + off);
#pragma unroll
            for (int nf = 0; nf < 2; ++nf) {
                ch[mf][nf] = __builtin_amdgcn_mfma_f32_16x16x32_f16(vh, pf[nf][0], ch[mf][nf], 0, 0, 0);
                cc[mf][nf] = __builtin_amdgcn_mfma_f32_16x16x32_f16(vh, pf[nf][1], cc[mf][nf], 0, 0, 0);
                cc[mf][nf] = __builtin_amdgcn_mfma_f32_16x16x32_f16(vl, pf[nf][0], cc[mf][nf], 0, 0, 0);
            }
        }
    }

    // ---- epilogue: emit cA planes (chunks of 4 consecutive d for fixed q)
#pragma unroll
    for (int mf = 0; mf < 4; ++mf)
#pragma unroll
        for (int nf = 0; nf < 2; ++nf) {
            int q = wv * 32 + nf * 16 + lm;
            int d0 = mf * 16 + g * 4;
            f16x4 hi, lo;
#pragma unroll
            for (int jj = 0; jj < 4; ++jj) {
                float x = ch[mf][nf][jj] + cc[mf][nf][jj] * inv;
                _Float16 hv = (_Float16)x;
                hi[jj] = hv; lo[jj] = (_Float16)((x - (float)hv) * 4096.f);
            }
            int kb = h * 2 + (d0 >> 5), koct = (d0 >> 3) & 3, half = (d0 >> 2) & 1;
            size_t eo = ((size_t)(b * 24 + kb)) * 4096
                      + (size_t)(q * 4 + (koct ^ (q & 3))) * 8 + half * 4;
            *(f16x4*)(cA_h + eo) = hi;
            *(f16x4*)(cA_l + eo) = lo;
        }
}

// ---------------- Viterbi ----------------
__global__ __launch_bounds__(64) void viterbi_kernel(
    const float* __restrict__ feats, const float* __restrict__ trans,
    float* __restrict__ out)
{
    __shared__ float tr[KT][KT];
    __shared__ unsigned char psi[TT - 1][BB][KT];
    int tid = threadIdx.x;
    if (tid < KT * KT) tr[tid / KT][tid % KT] = trans[tid];
    __syncthreads();
    if (tid < BB) {
        int b = tid;
        float ld[KT];
#pragma unroll
        for (int k = 0; k < KT; ++k) ld[k] = (k == START_TAG) ? 0.f : -10000.f;
        for (int t = 1; t < TT; ++t) {
            float nld[KT];
#pragma unroll
            for (int to = 0; to < KT; ++to) {
                float best = tr[to][0] + ld[0];
                int arg = 0;
#pragma unroll
                for (int fr = 1; fr < KT; ++fr) {
                    float v = tr[to][fr] + ld[fr];
                    if (v > best) { best = v; arg = fr; }
                }
                psi[t - 1][b][to] = (unsigned char)arg;
                nld[to] = best + feats[(size_t)(b * TT + t) * KT + to];
            }
#pragma unroll
            for (int k = 0; k < KT; ++k) ld[k] = nld[k];
        }
        float sc = ld[0]; int last = 0;
#pragma unroll
        for (int k = 1; k < KT; ++k) if (ld[k] > sc) { sc = ld[k]; last = k; }
        out[b] = sc;
        int p = last;
        out[BB + b * TT + (TT - 1)] = (float)last;
        for (int t = TT - 2; t >= 0; --t) {
            p = psi[t][b][p];
            out[BB + b * TT + t] = (float)p;
        }
    }
}

extern "C" void kernel_launch(void* const* d_in, const int* in_sizes, int n_in,
                              void* d_out, int out_size, void* d_ws, size_t ws_size,
                              hipStream_t stream) {
    const int*   sentence = (const int*)d_in[0];
    const int*   mask     = (const int*)d_in[1];
    const float* word_emb = (const float*)d_in[2];
    const float* pos_emb  = (const float*)d_in[3];
    const float* type_emb = (const float*)d_in[4];
    const float* emb_ln_s = (const float*)d_in[5];
    const float* emb_ln_b = (const float*)d_in[6];
    const float* Wqkv     = (const float*)d_in[7];
    const float* bqkv     = (const float*)d_in[8];
    const float* Wo       = (const float*)d_in[9];
    const float* bo       = (const float*)d_in[10];
    const float* ln1_s    = (const float*)d_in[11];
    const float* ln1_b    = (const float*)d_in[12];
    const float* W1       = (const float*)d_in[13];
    const float* b1       = (const float*)d_in[14];
    const float* W2       = (const float*)d_in[15];
    const float* b2       = (const float*)d_in[16];
    const float* ln2_s    = (const float*)d_in[17];
    const float* ln2_b    = (const float*)d_in[18];
    const float* Wt       = (const float*)d_in[19];
    const float* bt       = (const float*)d_in[20];
    const float* trans    = (const float*)d_in[21];

    char* base = (char*)d_ws;
    size_t off = 0;
    auto alloc = [&](size_t bytes) { void* p = base + off; off += (bytes + 255) & ~(size_t)255; return p; };

    // all-layer planes: 339.74 MB; activations: ~44.1 MB; total ~384 MB (ws=453 MB ok).
    bool allL = ws_size >= (384ULL << 20);
    int NLL = allL ? 12 : 1;

    _Float16* wq_h = (_Float16*)alloc((size_t)LQS * NLL * 2);
    _Float16* wq_l = (_Float16*)alloc((size_t)LQS * NLL * 2);
    _Float16* wo_h = (_Float16*)alloc((size_t)LOS * NLL * 2);
    _Float16* wo_l = (_Float16*)alloc((size_t)LOS * NLL * 2);
    _Float16* w1_h = (_Float16*)alloc((size_t)L1S * NLL * 2);
    _Float16* w1_l = (_Float16*)alloc((size_t)L1S * NLL * 2);
    _Float16* w2_h = (_Float16*)alloc((size_t)L2S * NLL * 2);
    _Float16* w2_l = (_Float16*)alloc((size_t)L2S * NLL * 2);
    float* h       = (float*)alloc((size_t)MTOK * HH * 4);
    _Float16* hA_h = (_Float16*)alloc((size_t)MTOK * HH * 2);
    _Float16* hA_l = (_Float16*)alloc((size_t)MTOK * HH * 2);
    _Float16* Qp_h = (_Float16*)alloc((size_t)96 * 8192 * 2);
    _Float16* Qp_l = (_Float16*)alloc((size_t)96 * 8192 * 2);
    _Float16* Kp_h = (_Float16*)alloc((size_t)96 * 8192 * 2);
    _Float16* Kp_l = (_Float16*)alloc((size_t)96 * 8192 * 2);
    float* vT      = (float*)alloc((size_t)96 * 8192 * 4);
    _Float16* cA_h = (_Float16*)alloc((size_t)MTOK * HH * 2);
    _Float16* cA_l = (_Float16*)alloc((size_t)MTOK * HH * 2);
    _Float16* gA_h = (_Float16*)alloc((size_t)MTOK * FFI * 2);
    _Float16* gA_l = (_Float16*)alloc((size_t)MTOK * FFI * 2);
    float* parts   = (float*)alloc((size_t)4 * MTOK * HH * 4);
    float* featsb  = (float*)alloc((size_t)MTOK * KT * 4);

    embed_ln_kernel<<<MTOK, 256, 0, stream>>>(sentence, word_emb, pos_emb, type_emb,
                                              emb_ln_s, emb_ln_b, h, hA_h, hA_l);
    if (allL) {
        wconv_kernel<1><<<41472, 256, 0, stream>>>(
            Wqkv, Wo, W1, W2, wq_h, wq_l, wo_h, wo_l, w1_h, w1_l, w2_h, w2_l);
    }
    for (int l = 0; l < LL; ++l) {
        size_t qO  = allL ? (size_t)l * LQS : 0;
        size_t oO  = allL ? (size_t)l * LOS : 0;
        size_t f1O = allL ? (size_t)l * L1S : 0;
        size_t f2O = allL ? (size_t)l * L2S : 0;
        if (!allL) {
            wconv_kernel<0><<<3456, 256, 0, stream>>>(
                Wqkv + (size_t)l * 768 * 2304, Wo + (size_t)l * 768 * 768,
                W1 + (size_t)l * 768 * 3072, W2 + (size_t)l * 3072 * 768,
                wq_h, wq_l, wo_h, wo_l, w1_h, w1_l, w2_h, w2_l);
        }
        // QKV transposed: -> Qp/Kp images + vT
        mfma_gemm<2><<<dim3(16, 18), 256, 0, stream>>>(
            wq_h + qO, wq_l + qO, hA_h, hA_l, bqkv + (size_t)l * 2304, vT,
            Qp_h, Qp_l, Kp_h, Kp_l, 2304, 24, 24);
        attn_mfma<<<96, 256, 0, stream>>>(Qp_h, Qp_l, Kp_h, Kp_l, vT, mask, cA_h, cA_l);
        // Wo: normal, split-K 4 -> parts
        mfma_gemm<0><<<dim3(12, 8, 4), 256, 0, stream>>>(
            cA_h, cA_l, wo_h + oO, wo_l + oO, nullptr, parts,
            nullptr, nullptr, nullptr, nullptr, 768, 24, 6);
        add_ln_red_kernel<0><<<MTOK, 256, 0, stream>>>(
            h, parts, bo + (size_t)l * HH, ln1_s + (size_t)l * HH, ln1_b + (size_t)l * HH,
            hA_h, hA_l, nullptr, nullptr, nullptr);
        // FF1 transposed + gelu -> gA planes
        mfma_gemm<3><<<dim3(16, 24), 256, 0, stream>>>(
            w1_h + f1O, w1_l + f1O, hA_h, hA_l, b1 + (size_t)l * FFI, nullptr,
            gA_h, gA_l, nullptr, nullptr, 3072, 24, 24);
        // FF2: normal, split-K 4 -> parts
        mfma_gemm<0><<<dim3(12, 8, 4), 256, 0, stream>>>(
            gA_h, gA_l, w2_h + f2O, w2_l + f2O, nullptr, parts,
            nullptr, nullptr, nullptr, nullptr, 768, 96, 24);
        if (l < LL - 1) {
            add_ln_red_kernel<0><<<MTOK, 256, 0, stream>>>(
                h, parts, b2 + (size_t)l * HH, ln2_s + (size_t)l * HH, ln2_b + (size_t)l * HH,
                hA_h, hA_l, nullptr, nullptr, nullptr);
        } else {
            add_ln_red_kernel<1><<<MTOK, 256, 0, stream>>>(
                h, parts, b2 + (size_t)l * HH, ln2_s + (size_t)l * HH, ln2_b + (size_t)l * HH,
                hA_h, hA_l, Wt, bt, featsb);
        }
    }
    viterbi_kernel<<<1, 64, 0, stream>>>(featsb, trans, (float*)d_out);
}

// Round 11
// 1492.123 us; speedup vs baseline: 1.2110x; 1.1034x over previous
//
#include <hip/hip_runtime.h>
#include <cstdint>
#include <cstddef>

#define BB 8
#define TT 128
#define LL 12
#define HH 768
#define NHH 12
#define DHH 64
#define FFI 3072
#define KT 5
#define START_TAG 3
#define MTOK (BB*TT)   // 1024

typedef _Float16 f16x8 __attribute__((ext_vector_type(8)));
typedef _Float16 f16x4 __attribute__((ext_vector_type(4)));
typedef float f32x4 __attribute__((ext_vector_type(4)));

// Measured-config notes (12 rounds of A/B on MI355X):
//  - GEMM inner loop: simple prefetch + __syncthreads is BEST (1496); counted
//    vmcnt/pinned variants +20..+47; the compiler's fine-grained lgkmcnt
//    scheduling wins.
//  - NO min-waves launch_bounds on register-fat kernels (forces spills:
//    +100..+180 us measured twice).
//  - Per-layer wconv (28MB buffer reused -> L3-resident) beats one all-layer
//    pass (340MB > L3, +~140 us measured).
//  - Mega-kernel/cooperative grid.sync costs ~30us/sync on 8 XCDs — dead end.

__device__ __forceinline__ void gl_lds16(const _Float16* g, _Float16* l) {
    __builtin_amdgcn_global_load_lds(
        (const __attribute__((address_space(1))) unsigned int*)g,
        (__attribute__((address_space(3))) unsigned int*)l, 16, 0, 0);
}

__device__ __forceinline__ float gelu_f(float x) {
    float c = 0.7978845608028654f * (x + 0.044715f * x * x * x);
    return 0.5f * x * (1.f + tanhf(c));
}

// write one 8-elem chunk of a normalized row into A-plane tiles (K=768, kTiles=24)
__device__ __forceinline__ void write_h_planes(const float* rowbuf, int tok,
                                               _Float16* dh, _Float16* dl, int c) {
    int kb = c >> 2;
    int rowm = tok & 127, mb = tok >> 7;
    int koct = c & 3;
    int p = rowm * 4 + (koct ^ (rowm & 3));
    size_t tb = ((size_t)(mb * 24 + kb)) * 4096;
    f16x8 vh, vl;
#pragma unroll
    for (int j = 0; j < 8; ++j) {
        float x = rowbuf[c * 8 + j];
        _Float16 hi = (_Float16)x;
        vh[j] = hi;
        vl[j] = (_Float16)((x - (float)hi) * 4096.f);
    }
    *(f16x8*)(dh + tb + (size_t)p * 8) = vh;
    *(f16x8*)(dl + tb + (size_t)p * 8) = vl;
}

// ---------------- embedding + LN (+A-plane emit) ----------------
__global__ __launch_bounds__(256) void embed_ln_kernel(
    const int* __restrict__ sentence,
    const float* __restrict__ word_emb,
    const float* __restrict__ pos_emb,
    const float* __restrict__ type_emb,
    const float* __restrict__ ln_s,
    const float* __restrict__ ln_b,
    float* __restrict__ h,
    _Float16* __restrict__ dh, _Float16* __restrict__ dl)
{
    int tok = blockIdx.x;
    int t = tok % TT;
    int id = sentence[tok];
    const float* we = word_emb + (size_t)id * HH;
    const float* pe = pos_emb + (size_t)t * HH;

    __shared__ float rowbuf[HH];
    __shared__ float rs_[4], rss_[4];
    float x[3];
    float s = 0.f, ss = 0.f;
#pragma unroll
    for (int i = 0; i < 3; ++i) {
        int d = threadIdx.x + i * 256;
        float v = we[d] + pe[d] + type_emb[d];
        x[i] = v; s += v; ss += v * v;
    }
    for (int o = 32; o; o >>= 1) { s += __shfl_down(s, o); ss += __shfl_down(ss, o); }
    int wid = threadIdx.x >> 6;
    if ((threadIdx.x & 63) == 0) { rs_[wid] = s; rss_[wid] = ss; }
    __syncthreads();
    s = rs_[0] + rs_[1] + rs_[2] + rs_[3];
    ss = rss_[0] + rss_[1] + rss_[2] + rss_[3];
    float mean = s * (1.f / HH);
    float var = ss * (1.f / HH) - mean * mean;
    float rstd = rsqrtf(var + 1e-12f);
#pragma unroll
    for (int i = 0; i < 3; ++i) {
        int d = threadIdx.x + i * 256;
        float y = (x[i] - mean) * rstd * ln_s[d] + ln_b[d];
        h[(size_t)tok * HH + d] = y;
        rowbuf[d] = y;
    }
    __syncthreads();
    if (threadIdx.x < 96) write_h_planes(rowbuf, tok, dh, dl, threadIdx.x);
}

// ---------------- split-K reduce + bias + residual + LN (+A-plane emit OR feats) ----------------
template<int FEATS>
__global__ __launch_bounds__(256) void add_ln_red_kernel(
    float* __restrict__ h, const float* __restrict__ parts,
    const float* __restrict__ bias,
    const float* __restrict__ ln_s, const float* __restrict__ ln_b,
    _Float16* __restrict__ dh, _Float16* __restrict__ dl,
    const float* __restrict__ Wt, const float* __restrict__ bt,
    float* __restrict__ feats)
{
    int tok = blockIdx.x;
    __shared__ float rowbuf[HH];
    __shared__ float rs_[4], rss_[4];
    float x[3];
    float s = 0.f, ss = 0.f;
#pragma unroll
    for (int i = 0; i < 3; ++i) {
        int d = threadIdx.x + i * 256;
        size_t idx = (size_t)tok * HH + d;
        float delta = parts[idx] + parts[idx + (size_t)MTOK * HH]
                    + parts[idx + 2 * (size_t)MTOK * HH] + parts[idx + 3 * (size_t)MTOK * HH]
                    + bias[d];
        float v = h[idx] + delta;
        x[i] = v; s += v; ss += v * v;
    }
    for (int o = 32; o; o >>= 1) { s += __shfl_down(s, o); ss += __shfl_down(ss, o); }
    int wid = threadIdx.x >> 6;
    if ((threadIdx.x & 63) == 0) { rs_[wid] = s; rss_[wid] = ss; }
    __syncthreads();
    s = rs_[0] + rs_[1] + rs_[2] + rs_[3];
    ss = rss_[0] + rss_[1] + rss_[2] + rss_[3];
    float mean = s * (1.f / HH);
    float var = ss * (1.f / HH) - mean * mean;
    float rstd = rsqrtf(var + 1e-12f);
    float yv[3];
#pragma unroll
    for (int i = 0; i < 3; ++i) {
        int d = threadIdx.x + i * 256;
        float y = (x[i] - mean) * rstd * ln_s[d] + ln_b[d];
        yv[i] = y;
        if constexpr (!FEATS) {
            h[(size_t)tok * HH + d] = y;
            rowbuf[d] = y;
        }
    }
    if constexpr (!FEATS) {
        __syncthreads();
        if (threadIdx.x < 96) write_h_planes(rowbuf, tok, dh, dl, threadIdx.x);
    } else {
        float pt[5] = {0.f, 0.f, 0.f, 0.f, 0.f};
#pragma unroll
        for (int i = 0; i < 3; ++i) {
            int d = threadIdx.x + i * 256;
#pragma unroll
            for (int t = 0; t < 5; ++t) pt[t] += yv[i] * Wt[d * 5 + t];
        }
#pragma unroll
        for (int t = 0; t < 5; ++t)
            for (int o = 32; o; o >>= 1) pt[t] += __shfl_down(pt[t], o);
        __shared__ float fred[4][5];
        if ((threadIdx.x & 63) == 0)
#pragma unroll
            for (int t = 0; t < 5; ++t) fred[wid][t] = pt[t];
        __syncthreads();
        if (threadIdx.x < 5) {
            float fs = fred[0][threadIdx.x] + fred[1][threadIdx.x]
                     + fred[2][threadIdx.x] + fred[3][threadIdx.x] + bt[threadIdx.x];
            feats[tok * 5 + threadIdx.x] = fs;
        }
    }
}

// ---------------- weight conversion: f32 [K][N] -> tiled/swizzled f16 hi/lo planes ----------------
// Per-layer (single-layer buffers stay L3-resident across the layer's GEMMs).
__global__ __launch_bounds__(256) void wconv_kernel(
    const float* __restrict__ Wqkv, const float* __restrict__ Wo,
    const float* __restrict__ W1, const float* __restrict__ W2,
    _Float16* __restrict__ qh, _Float16* __restrict__ ql,
    _Float16* __restrict__ oh, _Float16* __restrict__ ol,
    _Float16* __restrict__ f1h, _Float16* __restrict__ f1l,
    _Float16* __restrict__ f2h, _Float16* __restrict__ f2l)
{
    int b = blockIdx.x;
    const float* src; _Float16 *dh, *dl; int N, kTi, idx;
    if (b < 864)       { idx = b;        src = Wqkv; dh = qh;  dl = ql;  N = 2304; kTi = 24; }
    else if (b < 1152) { idx = b - 864;  src = Wo;   dh = oh;  dl = ol;  N = 768;  kTi = 24; }
    else if (b < 2304) { idx = b - 1152; src = W1;   dh = f1h; dl = f1l; N = 3072; kTi = 24; }
    else               { idx = b - 2304; src = W2;   dh = f2h; dl = f2l; N = 768;  kTi = 96; }
    int nb = idx / kTi, kb = idx % kTi;

    __shared__ float tile[32][65];
    const float* s0 = src + (size_t)(kb * 32) * N + nb * 64;
#pragma unroll
    for (int i = 0; i < 8; ++i) {
        int q = threadIdx.x + i * 256;
        int kk = q >> 6, n = q & 63;
        tile[kk][n] = s0[(size_t)kk * N + n];
    }
    __syncthreads();
    int p = threadIdx.x;
    int n = p >> 2, koct = (p & 3) ^ (n & 3);
    f16x8 vh, vl;
#pragma unroll
    for (int j = 0; j < 8; ++j) {
        float x = tile[koct * 8 + j][n];
        _Float16 hi = (_Float16)x;
        vh[j] = hi;
        vl[j] = (_Float16)((x - (float)hi) * 4096.f);
    }
    size_t tb = (size_t)idx * 2048;
    *(f16x8*)(dh + tb + (size_t)p * 8) = vh;
    *(f16x8*)(dl + tb + (size_t)p * 8) = vl;
}

// ---------------- split-f16 MFMA GEMM (normal + transposed variants) ----------------
// MODE 0: normal: A=act planes [128x32 tiles], B=weight planes [64x32 tiles],
//         out = fp32 split-K partials C[z][1024][N].
// MODE 2: transposed QKV: A=weight planes (M=2304), B=act planes (N=tok).
//         out: Q/K pre-swizzled f16 images (o1*,o2*) + V^T fp32 (outF). bias=bqkv.
// MODE 3: transposed FF1: bias+gelu, writes FF2 A-planes (o1*). bias=b1.
template<int MODE>
__global__ __launch_bounds__(256) void mfma_gemm(
    const _Float16* __restrict__ Ah, const _Float16* __restrict__ Al,
    const _Float16* __restrict__ Bh, const _Float16* __restrict__ Bl,
    const float* __restrict__ bias, float* __restrict__ outF,
    _Float16* __restrict__ o1h, _Float16* __restrict__ o1l,
    _Float16* __restrict__ o2h, _Float16* __restrict__ o2l,
    int N, int kTi, int kpz)
{
    constexpr bool TRANS = (MODE >= 2);
    __shared__ _Float16 lds[2][12288];   // A hi 4096 | A lo 4096 | B hi 2048 | B lo 2048
    int tid = threadIdx.x, lane = tid & 63, w = tid >> 6;
    int wm = w >> 1, wn = w & 1;
    int mb = blockIdx.y, nb = blockIdx.x;
    int ktBeg = TRANS ? 0 : blockIdx.z * kpz;
    int ktEnd = TRANS ? kTi : ktBeg + kpz;

    const _Float16 *aTh, *aTl, *bTh, *bTl;
    if constexpr (!TRANS) {
        aTh = Ah + (size_t)mb * kTi * 4096;
        aTl = Al + (size_t)mb * kTi * 4096;
        bTh = Bh + (size_t)nb * kTi * 2048;
        bTl = Bl + (size_t)nb * kTi * 2048;
    } else {
        aTh = Ah + (size_t)(2 * mb) * kTi * 2048;
        aTl = Al + (size_t)(2 * mb) * kTi * 2048;
        bTh = Bh + (size_t)(nb >> 1) * kTi * 4096 + (nb & 1) * 2048;
        bTl = Bl + (size_t)(nb >> 1) * kTi * 4096 + (nb & 1) * 2048;
    }

    f32x4 acch[4][2], accc[4][2];
#pragma unroll
    for (int i = 0; i < 4; ++i)
#pragma unroll
        for (int j = 0; j < 2; ++j) { acch[i][j] = (f32x4)0.f; accc[i][j] = (f32x4)0.f; }

    auto stage = [&](int buf, int kt) {
#pragma unroll
        for (int j = 0; j < 6; ++j) {
            int i = w * 6 + j;
            const _Float16* src;
            if constexpr (!TRANS) {
                if (i < 8)       src = aTh + (size_t)kt * 4096 + i * 512;
                else if (i < 16) src = aTl + (size_t)kt * 4096 + (i - 8) * 512;
                else if (i < 20) src = bTh + (size_t)kt * 2048 + (i - 16) * 512;
                else             src = bTl + (size_t)kt * 2048 + (i - 20) * 512;
            } else {
                if (i < 8)       src = aTh + (size_t)(i >> 2) * kTi * 2048 + (size_t)kt * 2048 + (i & 3) * 512;
                else if (i < 16) src = aTl + (size_t)((i - 8) >> 2) * kTi * 2048 + (size_t)kt * 2048 + ((i - 8) & 3) * 512;
                else if (i < 20) src = bTh + (size_t)kt * 4096 + (i - 16) * 512;
                else             src = bTl + (size_t)kt * 4096 + (i - 20) * 512;
            }
            gl_lds16(src + lane * 8, &lds[buf][i * 512]);
        }
    };

    stage(0, ktBeg);
    __syncthreads();
    int buf = 0;
    int lm = lane & 15, lk = lane >> 4;
    for (int kt = ktBeg; kt < ktEnd; ++kt) {
        if (kt + 1 < ktEnd) stage(buf ^ 1, kt + 1);
        const char* lb = (const char*)&lds[buf][0];
        f16x8 ahf[4], alf[4], bhf[2], blf[2];
#pragma unroll
        for (int mi = 0; mi < 4; ++mi) {
            int row = wm * 64 + mi * 16 + lm;
            int off = (row * 64 + lk * 16) ^ ((row & 3) << 4);
            ahf[mi] = *(const f16x8*)(lb + off);
            alf[mi] = *(const f16x8*)(lb + 8192 + off);
        }
#pragma unroll
        for (int ni = 0; ni < 2; ++ni) {
            int nr = wn * 32 + ni * 16 + lm;
            int off = (nr * 64 + lk * 16) ^ ((nr & 3) << 4);
            bhf[ni] = *(const f16x8*)(lb + 16384 + off);
            blf[ni] = *(const f16x8*)(lb + 20480 + off);
        }
#pragma unroll
        for (int mi = 0; mi < 4; ++mi)
#pragma unroll
            for (int ni = 0; ni < 2; ++ni) {
                acch[mi][ni] = __builtin_amdgcn_mfma_f32_16x16x32_f16(ahf[mi], bhf[ni], acch[mi][ni], 0, 0, 0);
                accc[mi][ni] = __builtin_amdgcn_mfma_f32_16x16x32_f16(ahf[mi], blf[ni], accc[mi][ni], 0, 0, 0);
                accc[mi][ni] = __builtin_amdgcn_mfma_f32_16x16x32_f16(alf[mi], bhf[ni], accc[mi][ni], 0, 0, 0);
            }
        __syncthreads();
        buf ^= 1;
    }

    const float inv = 1.0f / 4096.0f;
    if constexpr (MODE == 0) {
        float* Cz = outF + (size_t)blockIdx.z * 1024 * N;
#pragma unroll
        for (int mi = 0; mi < 4; ++mi)
#pragma unroll
            for (int ni = 0; ni < 2; ++ni) {
                int col = nb * 64 + wn * 32 + ni * 16 + lm;
                int r0 = mb * 128 + wm * 64 + mi * 16 + lk * 4;
#pragma unroll
                for (int j = 0; j < 4; ++j)
                    Cz[(size_t)(r0 + j) * N + col] = acch[mi][ni][j] + accc[mi][ni][j] * inv;
            }
    } else if constexpr (MODE == 2) {
        int region = mb / 6;   // 0=Q 1=K 2=V
#pragma unroll
        for (int mi = 0; mi < 4; ++mi)
#pragma unroll
            for (int ni = 0; ni < 2; ++ni) {
                int n = mb * 128 + wm * 64 + mi * 16 + lk * 4;
                int tok = nb * 64 + wn * 32 + ni * 16 + lm;
                float4 bv = *(const float4*)(bias + n);
                float v[4];
#pragma unroll
                for (int j = 0; j < 4; ++j)
                    v[j] = acch[mi][ni][j] + accc[mi][ni][j] * inv + (&bv.x)[j];
                int b = tok >> 7, q = tok & 127;
                if (region < 2) {
                    int hh2 = (n >> 6) % 12, d = n & 63;
                    size_t img = (size_t)(b * 12 + hh2);
                    _Float16* dsth = (region == 0) ? o1h : o2h;
                    _Float16* dstl = (region == 0) ? o1l : o2l;
                    int byteo = q * 128 + ((d * 2) ^ ((q & 7) << 4));
                    f16x4 hi, lo;
#pragma unroll
                    for (int j = 0; j < 4; ++j) {
                        _Float16 hv = (_Float16)v[j];
                        hi[j] = hv; lo[j] = (_Float16)((v[j] - (float)hv) * 4096.f);
                    }
                    *(f16x4*)((char*)dsth + img * 16384 + byteo) = hi;
                    *(f16x4*)((char*)dstl + img * 16384 + byteo) = lo;
                } else {
                    int hh2 = (n - 1536) >> 6, d = n & 63;
                    float* vdst = outF + (size_t)(b * 12 + hh2) * 8192;
#pragma unroll
                    for (int j = 0; j < 4; ++j)
                        vdst[(size_t)(d + j) * 128 + q] = v[j];
                }
            }
    } else { // MODE 3: FF1 transposed, bias+gelu -> gA planes
#pragma unroll
        for (int mi = 0; mi < 4; ++mi)
#pragma unroll
            for (int ni = 0; ni < 2; ++ni) {
                int n = mb * 128 + wm * 64 + mi * 16 + lk * 4;
                int tok = nb * 64 + wn * 32 + ni * 16 + lm;
                float4 bv = *(const float4*)(bias + n);
                int mbt = tok >> 7, rowm = tok & 127;
                int kb = n >> 5, koct = (n >> 3) & 3, half = (n >> 2) & 1;
                size_t eo = ((size_t)(mbt * 96 + kb)) * 4096
                          + (size_t)(rowm * 4 + (koct ^ (rowm & 3))) * 8 + half * 4;
                f16x4 hi, lo;
#pragma unroll
                for (int j = 0; j < 4; ++j) {
                    float x = gelu_f(acch[mi][ni][j] + accc[mi][ni][j] * inv + (&bv.x)[j]);
                    _Float16 hv = (_Float16)x;
                    hi[j] = hv; lo[j] = (_Float16)((x - (float)hv) * 4096.f);
                }
                *(f16x4*)(o1h + eo) = hi;
                *(f16x4*)(o1l + eo) = lo;
            }
    }
}

// ---------------- fused MFMA attention, one block per (b,h) ----------------
// (measured-best config: 96 blocks, 98816B LDS, no setprio, no min-waves)
__global__ __launch_bounds__(256, 1) void attn_mfma(
    const _Float16* __restrict__ Qp_h, const _Float16* __restrict__ Qp_l,
    const _Float16* __restrict__ Kp_h, const _Float16* __restrict__ Kp_l,
    const float* __restrict__ vT, const int* __restrict__ mask,
    _Float16* __restrict__ cA_h, _Float16* __restrict__ cA_l)
{
    __shared__ __align__(16) char sm[98816];
    char* Kh = sm;            char* Klo = sm + 16384;
    char* Qh = sm + 32768;    char* Qlo = sm + 49152;
    char* Ph = sm;            char* Plo = sm + 32768;    // reuse after barrier
    char* Vth = sm + 65536;   char* Vtl = sm + 81920;
    float* biasf = (float*)(sm + 98304);

    int bx = blockIdx.x; int b = bx / 12, h = bx % 12;
    int tid = threadIdx.x, lane = tid & 63, wv = tid >> 6;
    int lm = lane & 15, g = lane >> 4;
    const float inv = 1.0f / 4096.0f;

    {
        const _Float16* srcs[4] = { Kp_h + (size_t)bx * 8192, Kp_l + (size_t)bx * 8192,
                                    Qp_h + (size_t)bx * 8192, Qp_l + (size_t)bx * 8192 };
        char* dsts[4] = { Kh, Klo, Qh, Qlo };
#pragma unroll
        for (int p = 0; p < 4; ++p)
#pragma unroll
            for (int r = 0; r < 4; ++r) {
                int cbase = r * 256 + wv * 64;
                gl_lds16(srcs[p] + (size_t)(cbase + lane) * 8, (_Float16*)(dsts[p] + (size_t)cbase * 16));
            }
    }
    if (tid < 128) biasf[tid] = (1.f - (float)mask[b * 128 + tid]) * -10000.f;
    __syncthreads();

    // ---- QK^T: S^T[k][q], wave wv owns q-cols [wv*32, wv*32+32)
    f32x4 ah[8][2], ac[8][2];
#pragma unroll
    for (int i = 0; i < 8; ++i)
#pragma unroll
        for (int j = 0; j < 2; ++j) { ah[i][j] = (f32x4)0.f; ac[i][j] = (f32x4)0.f; }
#pragma unroll
    for (int ks = 0; ks < 2; ++ks) {
        f16x8 qf[2][2];
#pragma unroll
        for (int nf = 0; nf < 2; ++nf) {
            int q = wv * 32 + nf * 16 + lm;
            int off = (q * 128 + ks * 64 + g * 16) ^ ((q & 7) << 4);
            qf[nf][0] = *(const f16x8*)(Qh + off);
            qf[nf][1] = *(const f16x8*)(Qlo + off);
        }
#pragma unroll
        for (int mf = 0; mf < 8; ++mf) {
            int kt = mf * 16 + lm;
            int off = (kt * 128 + ks * 64 + g * 16) ^ ((kt & 7) << 4);
            f16x8 kh = *(const f16x8*)(Kh + off);
            f16x8 kl = *(const f16x8*)(Klo + off);
#pragma unroll
            for (int nf = 0; nf < 2; ++nf) {
                ah[mf][nf] = __builtin_amdgcn_mfma_f32_16x16x32_f16(kh, qf[nf][0], ah[mf][nf], 0, 0, 0);
                ac[mf][nf] = __builtin_amdgcn_mfma_f32_16x16x32_f16(kh, qf[nf][1], ac[mf][nf], 0, 0, 0);
                ac[mf][nf] = __builtin_amdgcn_mfma_f32_16x16x32_f16(kl, qf[nf][0], ac[mf][nf], 0, 0, 0);
            }
        }
    }

    float kb_[8][4];
#pragma unroll
    for (int mf = 0; mf < 8; ++mf)
#pragma unroll
        for (int jj = 0; jj < 4; ++jj) kb_[mf][jj] = biasf[mf * 16 + g * 4 + jj];

    float pv_[2][8][4], rs_[2];
#pragma unroll
    for (int nf = 0; nf < 2; ++nf) {
        float mx = -1e30f;
#pragma unroll
        for (int mf = 0; mf < 8; ++mf)
#pragma unroll
            for (int jj = 0; jj < 4; ++jj) {
                float s = (ah[mf][nf][jj] + ac[mf][nf][jj] * inv) * 0.125f + kb_[mf][jj];
                pv_[nf][mf][jj] = s;
                mx = fmaxf(mx, s);
            }
        mx = fmaxf(mx, __shfl_xor(mx, 16));
        mx = fmaxf(mx, __shfl_xor(mx, 32));
        float sum = 0.f;
#pragma unroll
        for (int mf = 0; mf < 8; ++mf)
#pragma unroll
            for (int jj = 0; jj < 4; ++jj) {
                float e = expf(pv_[nf][mf][jj] - mx);
                pv_[nf][mf][jj] = e;
                sum += e;
            }
        sum += __shfl_xor(sum, 16);
        sum += __shfl_xor(sum, 32);
        rs_[nf] = 1.f / sum;
    }
    __syncthreads();   // all waves done reading Q/K

    // write P planes [q][128k] f16 hi/lo, swizzled
#pragma unroll
    for (int nf = 0; nf < 2; ++nf) {
        int q = wv * 32 + nf * 16 + lm;
#pragma unroll
        for (int mf = 0; mf < 8; ++mf) {
            f16x4 hi, lo;
#pragma unroll
            for (int jj = 0; jj < 4; ++jj) {
                float p = pv_[nf][mf][jj] * rs_[nf];
                _Float16 hv = (_Float16)p;
                hi[jj] = hv; lo[jj] = (_Float16)((p - (float)hv) * 4096.f);
            }
            int byteo = (q * 256 + mf * 32 + g * 8) ^ ((q & 7) << 4);
            *(f16x4*)(Ph + byteo) = hi;
            *(f16x4*)(Plo + byteo) = lo;
        }
    }
    // stage V^T planes [d][128tok] from fp32 vT
    {
        int d = tid >> 2, tb = (tid & 3) * 32;
        const float* vsrc = vT + (size_t)bx * 8192 + (size_t)d * 128 + tb;
#pragma unroll
        for (int i = 0; i < 8; ++i) {
            float4 v = *(const float4*)(vsrc + i * 4);
            f16x4 hi, lo;
#pragma unroll
            for (int jj = 0; jj < 4; ++jj) {
                float x = (&v.x)[jj];
                _Float16 hv = (_Float16)x;
                hi[jj] = hv; lo[jj] = (_Float16)((x - (float)hv) * 4096.f);
            }
            int byteo = (d * 256 + (tb + i * 4) * 2) ^ ((d & 7) << 4);
            *(f16x4*)(Vth + byteo) = hi;
            *(f16x4*)(Vtl + byteo) = lo;
        }
    }
    __syncthreads();

    // ---- PV: ctx^T[d][q] = V^T @ P^T
    f32x4 ch[4][2], cc[4][2];
#pragma unroll
    for (int i = 0; i < 4; ++i)
#pragma unroll
        for (int j = 0; j < 2; ++j) { ch[i][j] = (f32x4)0.f; cc[i][j] = (f32x4)0.f; }
#pragma unroll
    for (int ks = 0; ks < 4; ++ks) {
        f16x8 pf[2][2];
#pragma unroll
        for (int nf = 0; nf < 2; ++nf) {
            int q = wv * 32 + nf * 16 + lm;
            int off = (q * 256 + ks * 64 + g * 16) ^ ((q & 7) << 4);
            pf[nf][0] = *(const f16x8*)(Ph + off);
            pf[nf][1] = *(const f16x8*)(Plo + off);
        }
#pragma unroll
        for (int mf = 0; mf < 4; ++mf) {
            int d = mf * 16 + lm;
            int off = (d * 256 + ks * 64 + g * 16) ^ ((d & 7) << 4);
            f16x8 vh = *(const f16x8*)(Vth + off);
            f16x8 vl = *(const f16x8*)(Vtl + off);
#pragma unroll
            for (int nf = 0; nf < 2; ++nf) {
                ch[mf][nf] = __builtin_amdgcn_mfma_f32_16x16x32_f16(vh, pf[nf][0], ch[mf][nf], 0, 0, 0);
                cc[mf][nf] = __builtin_amdgcn_mfma_f32_16x16x32_f16(vh, pf[nf][1], cc[mf][nf], 0, 0, 0);
                cc[mf][nf] = __builtin_amdgcn_mfma_f32_16x16x32_f16(vl, pf[nf][0], cc[mf][nf], 0, 0, 0);
            }
        }
    }

    // ---- epilogue: emit cA planes (chunks of 4 consecutive d for fixed q)
#pragma unroll
    for (int mf = 0; mf < 4; ++mf)
#pragma unroll
        for (int nf = 0; nf < 2; ++nf) {
            int q = wv * 32 + nf * 16 + lm;
            int d0 = mf * 16 + g * 4;
            f16x4 hi, lo;
#pragma unroll
            for (int jj = 0; jj < 4; ++jj) {
                float x = ch[mf][nf][jj] + cc[mf][nf][jj] * inv;
                _Float16 hv = (_Float16)x;
                hi[jj] = hv; lo[jj] = (_Float16)((x - (float)hv) * 4096.f);
            }
            int kb = h * 2 + (d0 >> 5), koct = (d0 >> 3) & 3, half = (d0 >> 2) & 1;
            size_t eo = ((size_t)(b * 24 + kb)) * 4096
                      + (size_t)(q * 4 + (koct ^ (q & 3))) * 8 + half * 4;
            *(f16x4*)(cA_h + eo) = hi;
            *(f16x4*)(cA_l + eo) = lo;
        }
}

// ---------------- Viterbi ----------------
__global__ __launch_bounds__(64) void viterbi_kernel(
    const float* __restrict__ feats, const float* __restrict__ trans,
    float* __restrict__ out)
{
    __shared__ float tr[KT][KT];
    __shared__ unsigned char psi[TT - 1][BB][KT];
    int tid = threadIdx.x;
    if (tid < KT * KT) tr[tid / KT][tid % KT] = trans[tid];
    __syncthreads();
    if (tid < BB) {
        int b = tid;
        float ld[KT];
#pragma unroll
        for (int k = 0; k < KT; ++k) ld[k] = (k == START_TAG) ? 0.f : -10000.f;
        for (int t = 1; t < TT; ++t) {
            float nld[KT];
#pragma unroll
            for (int to = 0; to < KT; ++to) {
                float best = tr[to][0] + ld[0];
                int arg = 0;
#pragma unroll
                for (int fr = 1; fr < KT; ++fr) {
                    float v = tr[to][fr] + ld[fr];
                    if (v > best) { best = v; arg = fr; }
                }
                psi[t - 1][b][to] = (unsigned char)arg;
                nld[to] = best + feats[(size_t)(b * TT + t) * KT + to];
            }
#pragma unroll
            for (int k = 0; k < KT; ++k) ld[k] = nld[k];
        }
        float sc = ld[0]; int last = 0;
#pragma unroll
        for (int k = 1; k < KT; ++k) if (ld[k] > sc) { sc = ld[k]; last = k; }
        out[b] = sc;
        int p = last;
        out[BB + b * TT + (TT - 1)] = (float)last;
        for (int t = TT - 2; t >= 0; --t) {
            p = psi[t][b][p];
            out[BB + b * TT + t] = (float)p;
        }
    }
}

extern "C" void kernel_launch(void* const* d_in, const int* in_sizes, int n_in,
                              void* d_out, int out_size, void* d_ws, size_t ws_size,
                              hipStream_t stream) {
    const int*   sentence = (const int*)d_in[0];
    const int*   mask     = (const int*)d_in[1];
    const float* word_emb = (const float*)d_in[2];
    const float* pos_emb  = (const float*)d_in[3];
    const float* type_emb = (const float*)d_in[4];
    const float* emb_ln_s = (const float*)d_in[5];
    const float* emb_ln_b = (const float*)d_in[6];
    const float* Wqkv     = (const float*)d_in[7];
    const float* bqkv     = (const float*)d_in[8];
    const float* Wo       = (const float*)d_in[9];
    const float* bo       = (const float*)d_in[10];
    const float* ln1_s    = (const float*)d_in[11];
    const float* ln1_b    = (const float*)d_in[12];
    const float* W1       = (const float*)d_in[13];
    const float* b1       = (const float*)d_in[14];
    const float* W2       = (const float*)d_in[15];
    const float* b2       = (const float*)d_in[16];
    const float* ln2_s    = (const float*)d_in[17];
    const float* ln2_b    = (const float*)d_in[18];
    const float* Wt       = (const float*)d_in[19];
    const float* bt       = (const float*)d_in[20];
    const float* trans    = (const float*)d_in[21];

    char* base = (char*)d_ws;
    size_t off = 0;
    auto alloc = [&](size_t bytes) { void* p = base + off; off += (bytes + 255) & ~(size_t)255; return p; };

    _Float16* wq_h = (_Float16*)alloc(768u * 2304 * 2);
    _Float16* wq_l = (_Float16*)alloc(768u * 2304 * 2);
    _Float16* wo_h = (_Float16*)alloc(768u * 768 * 2);
    _Float16* wo_l = (_Float16*)alloc(768u * 768 * 2);
    _Float16* w1_h = (_Float16*)alloc(768u * 3072 * 2);
    _Float16* w1_l = (_Float16*)alloc(768u * 3072 * 2);
    _Float16* w2_h = (_Float16*)alloc(3072u * 768 * 2);
    _Float16* w2_l = (_Float16*)alloc(3072u * 768 * 2);
    float* h       = (float*)alloc((size_t)MTOK * HH * 4);
    _Float16* hA_h = (_Float16*)alloc((size_t)MTOK * HH * 2);
    _Float16* hA_l = (_Float16*)alloc((size_t)MTOK * HH * 2);
    _Float16* Qp_h = (_Float16*)alloc((size_t)96 * 8192 * 2);
    _Float16* Qp_l = (_Float16*)alloc((size_t)96 * 8192 * 2);
    _Float16* Kp_h = (_Float16*)alloc((size_t)96 * 8192 * 2);
    _Float16* Kp_l = (_Float16*)alloc((size_t)96 * 8192 * 2);
    float* vT      = (float*)alloc((size_t)96 * 8192 * 4);
    _Float16* cA_h = (_Float16*)alloc((size_t)MTOK * HH * 2);
    _Float16* cA_l = (_Float16*)alloc((size_t)MTOK * HH * 2);
    _Float16* gA_h = (_Float16*)alloc((size_t)MTOK * FFI * 2);
    _Float16* gA_l = (_Float16*)alloc((size_t)MTOK * FFI * 2);
    float* parts   = (float*)alloc((size_t)4 * MTOK * HH * 4);
    float* featsb  = (float*)alloc((size_t)MTOK * KT * 4);

    embed_ln_kernel<<<MTOK, 256, 0, stream>>>(sentence, word_emb, pos_emb, type_emb,
                                              emb_ln_s, emb_ln_b, h, hA_h, hA_l);
    for (int l = 0; l < LL; ++l) {
        wconv_kernel<<<3456, 256, 0, stream>>>(
            Wqkv + (size_t)l * 768 * 2304, Wo + (size_t)l * 768 * 768,
            W1 + (size_t)l * 768 * 3072, W2 + (size_t)l * 3072 * 768,
            wq_h, wq_l, wo_h, wo_l, w1_h, w1_l, w2_h, w2_l);
        // QKV transposed: -> Qp/Kp images + vT
        mfma_gemm<2><<<dim3(16, 18), 256, 0, stream>>>(
            wq_h, wq_l, hA_h, hA_l, bqkv + (size_t)l * 2304, vT,
            Qp_h, Qp_l, Kp_h, Kp_l, 2304, 24, 24);
        attn_mfma<<<96, 256, 0, stream>>>(Qp_h, Qp_l, Kp_h, Kp_l, vT, mask, cA_h, cA_l);
        // Wo: normal, split-K 4 -> parts
        mfma_gemm<0><<<dim3(12, 8, 4), 256, 0, stream>>>(
            cA_h, cA_l, wo_h, wo_l, nullptr, parts,
            nullptr, nullptr, nullptr, nullptr, 768, 24, 6);
        add_ln_red_kernel<0><<<MTOK, 256, 0, stream>>>(
            h, parts, bo + (size_t)l * HH, ln1_s + (size_t)l * HH, ln1_b + (size_t)l * HH,
            hA_h, hA_l, nullptr, nullptr, nullptr);
        // FF1 transposed + gelu -> gA planes
        mfma_gemm<3><<<dim3(16, 24), 256, 0, stream>>>(
            w1_h, w1_l, hA_h, hA_l, b1 + (size_t)l * FFI, nullptr,
            gA_h, gA_l, nullptr, nullptr, 3072, 24, 24);
        // FF2: normal, split-K 4 -> parts
        mfma_gemm<0><<<dim3(12, 8, 4), 256, 0, stream>>>(
            gA_h, gA_l, w2_h, w2_l, nullptr, parts,
            nullptr, nullptr, nullptr, nullptr, 768, 96, 24);
        if (l < LL - 1) {
            add_ln_red_kernel<0><<<MTOK, 256, 0, stream>>>(
                h, parts, b2 + (size_t)l * HH, ln2_s + (size_t)l * HH, ln2_b + (size_t)l * HH,
                hA_h, hA_l, nullptr, nullptr, nullptr);
        } else {
            add_ln_red_kernel<1><<<MTOK, 256, 0, stream>>>(
                h, parts, b2 + (size_t)l * HH, ln2_s + (size_t)l * HH, ln2_b + (size_t)l * HH,
                hA_h, hA_l, Wt, bt, featsb);
        }
    }
    viterbi_kernel<<<1, 64, 0, stream>>>(featsb, trans, (float*)d_out);
}

// Round 12
// 1476.151 us; speedup vs baseline: 1.2241x; 1.0108x over previous
//
#include <hip/hip_runtime.h>
#include <cstdint>
#include <cstddef>

#define BB 8
#define TT 128
#define LL 12
#define HH 768
#define NHH 12
#define DHH 64
#define FFI 3072
#define KT 5
#define START_TAG 3
#define MTOK (BB*TT)   // 1024

typedef _Float16 f16x8 __attribute__((ext_vector_type(8)));
typedef _Float16 f16x4 __attribute__((ext_vector_type(4)));
typedef float f32x4 __attribute__((ext_vector_type(4)));

// Measured-config notes (12 rounds of A/B on MI355X):
//  - GEMM inner loop: simple prefetch + __syncthreads is BEST (1492-1496);
//    counted-vmcnt/pinned variants +20..+47.
//  - NO min-waves launch_bounds on register-fat kernels (spills: +100..+180us).
//  - Per-layer wconv (28MB, L3-resident) beats all-layer pass (+~140us).
//  - Mega-kernel grid.sync ~30us/sync — dead end.

__device__ __forceinline__ void gl_lds16(const _Float16* g, _Float16* l) {
    __builtin_amdgcn_global_load_lds(
        (const __attribute__((address_space(1))) unsigned int*)g,
        (__attribute__((address_space(3))) unsigned int*)l, 16, 0, 0);
}

__device__ __forceinline__ float gelu_f(float x) {
    float c = 0.7978845608028654f * (x + 0.044715f * x * x * x);
    return 0.5f * x * (1.f + tanhf(c));
}

// write one 8-elem chunk of a normalized row into A-plane tiles (K=768, kTiles=24)
__device__ __forceinline__ void write_h_planes(const float* rowbuf, int tok,
                                               _Float16* dh, _Float16* dl, int c) {
    int kb = c >> 2;
    int rowm = tok & 127, mb = tok >> 7;
    int koct = c & 3;
    int p = rowm * 4 + (koct ^ (rowm & 3));
    size_t tb = ((size_t)(mb * 24 + kb)) * 4096;
    f16x8 vh, vl;
#pragma unroll
    for (int j = 0; j < 8; ++j) {
        float x = rowbuf[c * 8 + j];
        _Float16 hi = (_Float16)x;
        vh[j] = hi;
        vl[j] = (_Float16)((x - (float)hi) * 4096.f);
    }
    *(f16x8*)(dh + tb + (size_t)p * 8) = vh;
    *(f16x8*)(dl + tb + (size_t)p * 8) = vl;
}

// ---------------- embedding + LN (+A-plane emit) ----------------
__global__ __launch_bounds__(256) void embed_ln_kernel(
    const int* __restrict__ sentence,
    const float* __restrict__ word_emb,
    const float* __restrict__ pos_emb,
    const float* __restrict__ type_emb,
    const float* __restrict__ ln_s,
    const float* __restrict__ ln_b,
    float* __restrict__ h,
    _Float16* __restrict__ dh, _Float16* __restrict__ dl)
{
    int tok = blockIdx.x;
    int t = tok % TT;
    int id = sentence[tok];
    const float* we = word_emb + (size_t)id * HH;
    const float* pe = pos_emb + (size_t)t * HH;

    __shared__ float rowbuf[HH];
    __shared__ float rs_[4], rss_[4];
    float x[3];
    float s = 0.f, ss = 0.f;
#pragma unroll
    for (int i = 0; i < 3; ++i) {
        int d = threadIdx.x + i * 256;
        float v = we[d] + pe[d] + type_emb[d];
        x[i] = v; s += v; ss += v * v;
    }
    for (int o = 32; o; o >>= 1) { s += __shfl_down(s, o); ss += __shfl_down(ss, o); }
    int wid = threadIdx.x >> 6;
    if ((threadIdx.x & 63) == 0) { rs_[wid] = s; rss_[wid] = ss; }
    __syncthreads();
    s = rs_[0] + rs_[1] + rs_[2] + rs_[3];
    ss = rss_[0] + rss_[1] + rss_[2] + rss_[3];
    float mean = s * (1.f / HH);
    float var = ss * (1.f / HH) - mean * mean;
    float rstd = rsqrtf(var + 1e-12f);
#pragma unroll
    for (int i = 0; i < 3; ++i) {
        int d = threadIdx.x + i * 256;
        float y = (x[i] - mean) * rstd * ln_s[d] + ln_b[d];
        h[(size_t)tok * HH + d] = y;
        rowbuf[d] = y;
    }
    __syncthreads();
    if (threadIdx.x < 96) write_h_planes(rowbuf, tok, dh, dl, threadIdx.x);
}

// ---------------- split-K reduce + bias + residual + LN (+A-plane emit OR feats) ----------------
template<int FEATS>
__global__ __launch_bounds__(256) void add_ln_red_kernel(
    float* __restrict__ h, const float* __restrict__ parts,
    const float* __restrict__ bias,
    const float* __restrict__ ln_s, const float* __restrict__ ln_b,
    _Float16* __restrict__ dh, _Float16* __restrict__ dl,
    const float* __restrict__ Wt, const float* __restrict__ bt,
    float* __restrict__ feats)
{
    int tok = blockIdx.x;
    __shared__ float rowbuf[HH];
    __shared__ float rs_[4], rss_[4];
    float x[3];
    float s = 0.f, ss = 0.f;
#pragma unroll
    for (int i = 0; i < 3; ++i) {
        int d = threadIdx.x + i * 256;
        size_t idx = (size_t)tok * HH + d;
        float delta = parts[idx] + parts[idx + (size_t)MTOK * HH]
                    + parts[idx + 2 * (size_t)MTOK * HH] + parts[idx + 3 * (size_t)MTOK * HH]
                    + bias[d];
        float v = h[idx] + delta;
        x[i] = v; s += v; ss += v * v;
    }
    for (int o = 32; o; o >>= 1) { s += __shfl_down(s, o); ss += __shfl_down(ss, o); }
    int wid = threadIdx.x >> 6;
    if ((threadIdx.x & 63) == 0) { rs_[wid] = s; rss_[wid] = ss; }
    __syncthreads();
    s = rs_[0] + rs_[1] + rs_[2] + rs_[3];
    ss = rss_[0] + rss_[1] + rss_[2] + rss_[3];
    float mean = s * (1.f / HH);
    float var = ss * (1.f / HH) - mean * mean;
    float rstd = rsqrtf(var + 1e-12f);
    float yv[3];
#pragma unroll
    for (int i = 0; i < 3; ++i) {
        int d = threadIdx.x + i * 256;
        float y = (x[i] - mean) * rstd * ln_s[d] + ln_b[d];
        yv[i] = y;
        if constexpr (!FEATS) {
            h[(size_t)tok * HH + d] = y;
            rowbuf[d] = y;
        }
    }
    if constexpr (!FEATS) {
        __syncthreads();
        if (threadIdx.x < 96) write_h_planes(rowbuf, tok, dh, dl, threadIdx.x);
    } else {
        float pt[5] = {0.f, 0.f, 0.f, 0.f, 0.f};
#pragma unroll
        for (int i = 0; i < 3; ++i) {
            int d = threadIdx.x + i * 256;
#pragma unroll
            for (int t = 0; t < 5; ++t) pt[t] += yv[i] * Wt[d * 5 + t];
        }
#pragma unroll
        for (int t = 0; t < 5; ++t)
            for (int o = 32; o; o >>= 1) pt[t] += __shfl_down(pt[t], o);
        __shared__ float fred[4][5];
        if ((threadIdx.x & 63) == 0)
#pragma unroll
            for (int t = 0; t < 5; ++t) fred[wid][t] = pt[t];
        __syncthreads();
        if (threadIdx.x < 5) {
            float fs = fred[0][threadIdx.x] + fred[1][threadIdx.x]
                     + fred[2][threadIdx.x] + fred[3][threadIdx.x] + bt[threadIdx.x];
            feats[tok * 5 + threadIdx.x] = fs;
        }
    }
}

// ---------------- weight conversion: f32 [K][N] -> tiled/swizzled f16 hi/lo planes ----------------
__global__ __launch_bounds__(256) void wconv_kernel(
    const float* __restrict__ Wqkv, const float* __restrict__ Wo,
    const float* __restrict__ W1, const float* __restrict__ W2,
    _Float16* __restrict__ qh, _Float16* __restrict__ ql,
    _Float16* __restrict__ oh, _Float16* __restrict__ ol,
    _Float16* __restrict__ f1h, _Float16* __restrict__ f1l,
    _Float16* __restrict__ f2h, _Float16* __restrict__ f2l)
{
    int b = blockIdx.x;
    const float* src; _Float16 *dh, *dl; int N, kTi, idx;
    if (b < 864)       { idx = b;        src = Wqkv; dh = qh;  dl = ql;  N = 2304; kTi = 24; }
    else if (b < 1152) { idx = b - 864;  src = Wo;   dh = oh;  dl = ol;  N = 768;  kTi = 24; }
    else if (b < 2304) { idx = b - 1152; src = W1;   dh = f1h; dl = f1l; N = 3072; kTi = 24; }
    else               { idx = b - 2304; src = W2;   dh = f2h; dl = f2l; N = 768;  kTi = 96; }
    int nb = idx / kTi, kb = idx % kTi;

    __shared__ float tile[32][65];
    const float* s0 = src + (size_t)(kb * 32) * N + nb * 64;
#pragma unroll
    for (int i = 0; i < 8; ++i) {
        int q = threadIdx.x + i * 256;
        int kk = q >> 6, n = q & 63;
        tile[kk][n] = s0[(size_t)kk * N + n];
    }
    __syncthreads();
    int p = threadIdx.x;
    int n = p >> 2, koct = (p & 3) ^ (n & 3);
    f16x8 vh, vl;
#pragma unroll
    for (int j = 0; j < 8; ++j) {
        float x = tile[koct * 8 + j][n];
        _Float16 hi = (_Float16)x;
        vh[j] = hi;
        vl[j] = (_Float16)((x - (float)hi) * 4096.f);
    }
    size_t tb = (size_t)idx * 2048;
    *(f16x8*)(dh + tb + (size_t)p * 8) = vh;
    *(f16x8*)(dl + tb + (size_t)p * 8) = vl;
}

// ---------------- split-f16 MFMA GEMM (normal + transposed variants) ----------------
template<int MODE>
__global__ __launch_bounds__(256) void mfma_gemm(
    const _Float16* __restrict__ Ah, const _Float16* __restrict__ Al,
    const _Float16* __restrict__ Bh, const _Float16* __restrict__ Bl,
    const float* __restrict__ bias, float* __restrict__ outF,
    _Float16* __restrict__ o1h, _Float16* __restrict__ o1l,
    _Float16* __restrict__ o2h, _Float16* __restrict__ o2l,
    int N, int kTi, int kpz)
{
    constexpr bool TRANS = (MODE >= 2);
    __shared__ _Float16 lds[2][12288];   // A hi 4096 | A lo 4096 | B hi 2048 | B lo 2048
    int tid = threadIdx.x, lane = tid & 63, w = tid >> 6;
    int wm = w >> 1, wn = w & 1;
    int mb = blockIdx.y, nb = blockIdx.x;
    int ktBeg = TRANS ? 0 : blockIdx.z * kpz;
    int ktEnd = TRANS ? kTi : ktBeg + kpz;

    const _Float16 *aTh, *aTl, *bTh, *bTl;
    if constexpr (!TRANS) {
        aTh = Ah + (size_t)mb * kTi * 4096;
        aTl = Al + (size_t)mb * kTi * 4096;
        bTh = Bh + (size_t)nb * kTi * 2048;
        bTl = Bl + (size_t)nb * kTi * 2048;
    } else {
        aTh = Ah + (size_t)(2 * mb) * kTi * 2048;
        aTl = Al + (size_t)(2 * mb) * kTi * 2048;
        bTh = Bh + (size_t)(nb >> 1) * kTi * 4096 + (nb & 1) * 2048;
        bTl = Bl + (size_t)(nb >> 1) * kTi * 4096 + (nb & 1) * 2048;
    }

    f32x4 acch[4][2], accc[4][2];
#pragma unroll
    for (int i = 0; i < 4; ++i)
#pragma unroll
        for (int j = 0; j < 2; ++j) { acch[i][j] = (f32x4)0.f; accc[i][j] = (f32x4)0.f; }

    auto stage = [&](int buf, int kt) {
#pragma unroll
        for (int j = 0; j < 6; ++j) {
            int i = w * 6 + j;
            const _Float16* src;
            if constexpr (!TRANS) {
                if (i < 8)       src = aTh + (size_t)kt * 4096 + i * 512;
                else if (i < 16) src = aTl + (size_t)kt * 4096 + (i - 8) * 512;
                else if (i < 20) src = bTh + (size_t)kt * 2048 + (i - 16) * 512;
                else             src = bTl + (size_t)kt * 2048 + (i - 20) * 512;
            } else {
                if (i < 8)       src = aTh + (size_t)(i >> 2) * kTi * 2048 + (size_t)kt * 2048 + (i & 3) * 512;
                else if (i < 16) src = aTl + (size_t)((i - 8) >> 2) * kTi * 2048 + (size_t)kt * 2048 + ((i - 8) & 3) * 512;
                else if (i < 20) src = bTh + (size_t)kt * 4096 + (i - 16) * 512;
                else             src = bTl + (size_t)kt * 4096 + (i - 20) * 512;
            }
            gl_lds16(src + lane * 8, &lds[buf][i * 512]);
        }
    };

    stage(0, ktBeg);
    __syncthreads();
    int buf = 0;
    int lm = lane & 15, lk = lane >> 4;
    for (int kt = ktBeg; kt < ktEnd; ++kt) {
        if (kt + 1 < ktEnd) stage(buf ^ 1, kt + 1);
        const char* lb = (const char*)&lds[buf][0];
        f16x8 ahf[4], alf[4], bhf[2], blf[2];
#pragma unroll
        for (int mi = 0; mi < 4; ++mi) {
            int row = wm * 64 + mi * 16 + lm;
            int off = (row * 64 + lk * 16) ^ ((row & 3) << 4);
            ahf[mi] = *(const f16x8*)(lb + off);
            alf[mi] = *(const f16x8*)(lb + 8192 + off);
        }
#pragma unroll
        for (int ni = 0; ni < 2; ++ni) {
            int nr = wn * 32 + ni * 16 + lm;
            int off = (nr * 64 + lk * 16) ^ ((nr & 3) << 4);
            bhf[ni] = *(const f16x8*)(lb + 16384 + off);
            blf[ni] = *(const f16x8*)(lb + 20480 + off);
        }
#pragma unroll
        for (int mi = 0; mi < 4; ++mi)
#pragma unroll
            for (int ni = 0; ni < 2; ++ni) {
                acch[mi][ni] = __builtin_amdgcn_mfma_f32_16x16x32_f16(ahf[mi], bhf[ni], acch[mi][ni], 0, 0, 0);
                accc[mi][ni] = __builtin_amdgcn_mfma_f32_16x16x32_f16(ahf[mi], blf[ni], accc[mi][ni], 0, 0, 0);
                accc[mi][ni] = __builtin_amdgcn_mfma_f32_16x16x32_f16(alf[mi], bhf[ni], accc[mi][ni], 0, 0, 0);
            }
        __syncthreads();
        buf ^= 1;
    }

    const float inv = 1.0f / 4096.0f;
    if constexpr (MODE == 0) {
        float* Cz = outF + (size_t)blockIdx.z * 1024 * N;
#pragma unroll
        for (int mi = 0; mi < 4; ++mi)
#pragma unroll
            for (int ni = 0; ni < 2; ++ni) {
                int col = nb * 64 + wn * 32 + ni * 16 + lm;
                int r0 = mb * 128 + wm * 64 + mi * 16 + lk * 4;
#pragma unroll
                for (int j = 0; j < 4; ++j)
                    Cz[(size_t)(r0 + j) * N + col] = acch[mi][ni][j] + accc[mi][ni][j] * inv;
            }
    } else if constexpr (MODE == 2) {
        int region = mb / 6;   // 0=Q 1=K 2=V
#pragma unroll
        for (int mi = 0; mi < 4; ++mi)
#pragma unroll
            for (int ni = 0; ni < 2; ++ni) {
                int n = mb * 128 + wm * 64 + mi * 16 + lk * 4;
                int tok = nb * 64 + wn * 32 + ni * 16 + lm;
                float4 bv = *(const float4*)(bias + n);
                float v[4];
#pragma unroll
                for (int j = 0; j < 4; ++j)
                    v[j] = acch[mi][ni][j] + accc[mi][ni][j] * inv + (&bv.x)[j];
                int b = tok >> 7, q = tok & 127;
                if (region < 2) {
                    int hh2 = (n >> 6) % 12, d = n & 63;
                    size_t img = (size_t)(b * 12 + hh2);
                    _Float16* dsth = (region == 0) ? o1h : o2h;
                    _Float16* dstl = (region == 0) ? o1l : o2l;
                    int byteo = q * 128 + ((d * 2) ^ ((q & 7) << 4));
                    f16x4 hi, lo;
#pragma unroll
                    for (int j = 0; j < 4; ++j) {
                        _Float16 hv = (_Float16)v[j];
                        hi[j] = hv; lo[j] = (_Float16)((v[j] - (float)hv) * 4096.f);
                    }
                    *(f16x4*)((char*)dsth + img * 16384 + byteo) = hi;
                    *(f16x4*)((char*)dstl + img * 16384 + byteo) = lo;
                } else {
                    int hh2 = (n - 1536) >> 6, d = n & 63;
                    float* vdst = outF + (size_t)(b * 12 + hh2) * 8192;
#pragma unroll
                    for (int j = 0; j < 4; ++j)
                        vdst[(size_t)(d + j) * 128 + q] = v[j];
                }
            }
    } else { // MODE 3: FF1 transposed, bias+gelu -> gA planes
#pragma unroll
        for (int mi = 0; mi < 4; ++mi)
#pragma unroll
            for (int ni = 0; ni < 2; ++ni) {
                int n = mb * 128 + wm * 64 + mi * 16 + lk * 4;
                int tok = nb * 64 + wn * 32 + ni * 16 + lm;
                float4 bv = *(const float4*)(bias + n);
                int mbt = tok >> 7, rowm = tok & 127;
                int kb = n >> 5, koct = (n >> 3) & 3, half = (n >> 2) & 1;
                size_t eo = ((size_t)(mbt * 96 + kb)) * 4096
                          + (size_t)(rowm * 4 + (koct ^ (rowm & 3))) * 8 + half * 4;
                f16x4 hi, lo;
#pragma unroll
                for (int j = 0; j < 4; ++j) {
                    float x = gelu_f(acch[mi][ni][j] + accc[mi][ni][j] * inv + (&bv.x)[j]);
                    _Float16 hv = (_Float16)x;
                    hi[j] = hv; lo[j] = (_Float16)((x - (float)hv) * 4096.f);
                }
                *(f16x4*)(o1h + eo) = hi;
                *(f16x4*)(o1l + eo) = lo;
            }
    }
}

// ---------------- fused MFMA attention, one block per (b,h,q-half) ----------------
// q-split: 192 blocks (75% CU fill vs 37% at 96); validated in r5/r6 bundles.
__global__ __launch_bounds__(256, 1) void attn_mfma(
    const _Float16* __restrict__ Qp_h, const _Float16* __restrict__ Qp_l,
    const _Float16* __restrict__ Kp_h, const _Float16* __restrict__ Kp_l,
    const float* __restrict__ vT, const int* __restrict__ mask,
    _Float16* __restrict__ cA_h, _Float16* __restrict__ cA_l)
{
    __shared__ __align__(16) char sm[82432];
    char* Kh  = sm;             char* Klo = sm + 16384;
    char* Qh  = sm + 32768;     char* Qlo = sm + 40960;
    char* Ph  = sm;             char* Plo = sm + 16384;   // reuse K region after QK^T
    char* Vth = sm + 49152;     char* Vtl = sm + 65536;
    float* biasf = (float*)(sm + 81920);

    int bx = blockIdx.x;               // 0..191
    int bh = bx >> 1, qh2 = bx & 1;
    int b = bh / 12, h = bh % 12;
    int q0 = qh2 * 64;
    int tid = threadIdx.x, lane = tid & 63, wv = tid >> 6;
    int lm = lane & 15, g = lane >> 4;
    int qr = wv * 16 + lm;             // local q row 0..63
    const float inv = 1.0f / 4096.0f;

    {
        const _Float16* Ksh = Kp_h + (size_t)bh * 8192;
        const _Float16* Ksl = Kp_l + (size_t)bh * 8192;
        const _Float16* Qsh = Qp_h + (size_t)bh * 8192 + (size_t)q0 * 64;
        const _Float16* Qsl = Qp_l + (size_t)bh * 8192 + (size_t)q0 * 64;
#pragma unroll
        for (int i = 0; i < 4; ++i) {
            gl_lds16(Ksh + (size_t)(i * 256 + tid) * 8, (_Float16*)(Kh  + (i * 256 + tid) * 16));
            gl_lds16(Ksl + (size_t)(i * 256 + tid) * 8, (_Float16*)(Klo + (i * 256 + tid) * 16));
        }
#pragma unroll
        for (int i = 0; i < 2; ++i) {
            gl_lds16(Qsh + (size_t)(i * 256 + tid) * 8, (_Float16*)(Qh  + (i * 256 + tid) * 16));
            gl_lds16(Qsl + (size_t)(i * 256 + tid) * 8, (_Float16*)(Qlo + (i * 256 + tid) * 16));
        }
    }
    if (tid < 128) biasf[tid] = (1.f - (float)mask[b * 128 + tid]) * -10000.f;
    __syncthreads();

    // ---- QK^T: S^T[k=128][q=64], each wave owns 16 q-cols
    f32x4 ah[8], ac[8];
#pragma unroll
    for (int i = 0; i < 8; ++i) { ah[i] = (f32x4)0.f; ac[i] = (f32x4)0.f; }
    __builtin_amdgcn_s_setprio(1);
#pragma unroll
    for (int ks = 0; ks < 2; ++ks) {
        int qoff = qr * 128 + ((ks * 64 + g * 16) ^ ((qr & 7) << 4));
        f16x8 q_h = *(const f16x8*)(Qh + qoff);
        f16x8 q_l = *(const f16x8*)(Qlo + qoff);
#pragma unroll
        for (int mf = 0; mf < 8; ++mf) {
            int kt = mf * 16 + lm;
            int koff = kt * 128 + ((ks * 64 + g * 16) ^ ((kt & 7) << 4));
            f16x8 k_h = *(const f16x8*)(Kh + koff);
            f16x8 k_l = *(const f16x8*)(Klo + koff);
            ah[mf] = __builtin_amdgcn_mfma_f32_16x16x32_f16(k_h, q_h, ah[mf], 0, 0, 0);
            ac[mf] = __builtin_amdgcn_mfma_f32_16x16x32_f16(k_h, q_l, ac[mf], 0, 0, 0);
            ac[mf] = __builtin_amdgcn_mfma_f32_16x16x32_f16(k_l, q_h, ac[mf], 0, 0, 0);
        }
    }
    __builtin_amdgcn_s_setprio(0);

    float kb_[8][4];
#pragma unroll
    for (int mf = 0; mf < 8; ++mf)
#pragma unroll
        for (int jj = 0; jj < 4; ++jj) kb_[mf][jj] = biasf[mf * 16 + g * 4 + jj];

    float pv_[8][4];
    float mx = -1e30f;
#pragma unroll
    for (int mf = 0; mf < 8; ++mf)
#pragma unroll
        for (int jj = 0; jj < 4; ++jj) {
            float s = (ah[mf][jj] + ac[mf][jj] * inv) * 0.125f + kb_[mf][jj];
            pv_[mf][jj] = s;
            mx = fmaxf(mx, s);
        }
    mx = fmaxf(mx, __shfl_xor(mx, 16));
    mx = fmaxf(mx, __shfl_xor(mx, 32));
    float sum = 0.f;
#pragma unroll
    for (int mf = 0; mf < 8; ++mf)
#pragma unroll
        for (int jj = 0; jj < 4; ++jj) {
            float e = expf(pv_[mf][jj] - mx);
            pv_[mf][jj] = e;
            sum += e;
        }
    sum += __shfl_xor(sum, 16);
    sum += __shfl_xor(sum, 32);
    float rs = 1.f / sum;
    __syncthreads();   // all waves done reading Q/K before P overwrites

    // write P planes [qr][128k] f16 hi/lo, swizzled
#pragma unroll
    for (int mf = 0; mf < 8; ++mf) {
        f16x4 hi, lo;
#pragma unroll
        for (int jj = 0; jj < 4; ++jj) {
            float p = pv_[mf][jj] * rs;
            _Float16 hv = (_Float16)p;
            hi[jj] = hv; lo[jj] = (_Float16)((p - (float)hv) * 4096.f);
        }
        int byteo = qr * 256 + ((mf * 32 + g * 8) ^ ((qr & 7) << 4));
        *(f16x4*)(Ph + byteo) = hi;
        *(f16x4*)(Plo + byteo) = lo;
    }
    // stage V^T planes [d][128tok] from fp32 vT
    {
        int d = tid >> 2, tb = (tid & 3) * 32;
        const float* vsrc = vT + (size_t)bh * 8192 + (size_t)d * 128 + tb;
#pragma unroll
        for (int i = 0; i < 8; ++i) {
            float4 v = *(const float4*)(vsrc + i * 4);
            f16x4 hi, lo;
#pragma unroll
            for (int jj = 0; jj < 4; ++jj) {
                float x = (&v.x)[jj];
                _Float16 hv = (_Float16)x;
                hi[jj] = hv; lo[jj] = (_Float16)((x - (float)hv) * 4096.f);
            }
            int byteo = d * 256 + (((tb + i * 4) * 2) ^ ((d & 7) << 4));
            *(f16x4*)(Vth + byteo) = hi;
            *(f16x4*)(Vtl + byteo) = lo;
        }
    }
    __syncthreads();

    // ---- PV: ctx^T[d=64][q=64] = V^T @ P^T
    f32x4 ch[4], cc[4];
#pragma unroll
    for (int i = 0; i < 4; ++i) { ch[i] = (f32x4)0.f; cc[i] = (f32x4)0.f; }
    __builtin_amdgcn_s_setprio(1);
#pragma unroll
    for (int ks = 0; ks < 4; ++ks) {
        int poff = qr * 256 + ((ks * 64 + g * 16) ^ ((qr & 7) << 4));
        f16x8 p_h = *(const f16x8*)(Ph + poff);
        f16x8 p_l = *(const f16x8*)(Plo + poff);
#pragma unroll
        for (int mf = 0; mf < 4; ++mf) {
            int d = mf * 16 + lm;
            int voff = d * 256 + ((ks * 64 + g * 16) ^ ((d & 7) << 4));
            f16x8 vh = *(const f16x8*)(Vth + voff);
            f16x8 vl = *(const f16x8*)(Vtl + voff);
            ch[mf] = __builtin_amdgcn_mfma_f32_16x16x32_f16(vh, p_h, ch[mf], 0, 0, 0);
            cc[mf] = __builtin_amdgcn_mfma_f32_16x16x32_f16(vh, p_l, cc[mf], 0, 0, 0);
            cc[mf] = __builtin_amdgcn_mfma_f32_16x16x32_f16(vl, p_h, cc[mf], 0, 0, 0);
        }
    }
    __builtin_amdgcn_s_setprio(0);

    // ---- epilogue: emit cA planes
    int q = q0 + qr;
#pragma unroll
    for (int mf = 0; mf < 4; ++mf) {
        int d0 = mf * 16 + g * 4;
        f16x4 hi, lo;
#pragma unroll
        for (int jj = 0; jj < 4; ++jj) {
            float x = ch[mf][jj] + cc[mf][jj] * inv;
            _Float16 hv = (_Float16)x;
            hi[jj] = hv; lo[jj] = (_Float16)((x - (float)hv) * 4096.f);
        }
        int kb = h * 2 + (d0 >> 5), koct = (d0 >> 3) & 3, half = (d0 >> 2) & 1;
        size_t eo = ((size_t)(b * 24 + kb)) * 4096
                  + (size_t)(q * 4 + (koct ^ (q & 3))) * 8 + half * 4;
        *(f16x4*)(cA_h + eo) = hi;
        *(f16x4*)(cA_l + eo) = lo;
    }
}

// ---------------- Viterbi ----------------
__global__ __launch_bounds__(64) void viterbi_kernel(
    const float* __restrict__ feats, const float* __restrict__ trans,
    float* __restrict__ out)
{
    __shared__ float tr[KT][KT];
    __shared__ unsigned char psi[TT - 1][BB][KT];
    int tid = threadIdx.x;
    if (tid < KT * KT) tr[tid / KT][tid % KT] = trans[tid];
    __syncthreads();
    if (tid < BB) {
        int b = tid;
        float ld[KT];
#pragma unroll
        for (int k = 0; k < KT; ++k) ld[k] = (k == START_TAG) ? 0.f : -10000.f;
        for (int t = 1; t < TT; ++t) {
            float nld[KT];
#pragma unroll
            for (int to = 0; to < KT; ++to) {
                float best = tr[to][0] + ld[0];
                int arg = 0;
#pragma unroll
                for (int fr = 1; fr < KT; ++fr) {
                    float v = tr[to][fr] + ld[fr];
                    if (v > best) { best = v; arg = fr; }
                }
                psi[t - 1][b][to] = (unsigned char)arg;
                nld[to] = best + feats[(size_t)(b * TT + t) * KT + to];
            }
#pragma unroll
            for (int k = 0; k < KT; ++k) ld[k] = nld[k];
        }
        float sc = ld[0]; int last = 0;
#pragma unroll
        for (int k = 1; k < KT; ++k) if (ld[k] > sc) { sc = ld[k]; last = k; }
        out[b] = sc;
        int p = last;
        out[BB + b * TT + (TT - 1)] = (float)last;
        for (int t = TT - 2; t >= 0; --t) {
            p = psi[t][b][p];
            out[BB + b * TT + t] = (float)p;
        }
    }
}

extern "C" void kernel_launch(void* const* d_in, const int* in_sizes, int n_in,
                              void* d_out, int out_size, void* d_ws, size_t ws_size,
                              hipStream_t stream) {
    const int*   sentence = (const int*)d_in[0];
    const int*   mask     = (const int*)d_in[1];
    const float* word_emb = (const float*)d_in[2];
    const float* pos_emb  = (const float*)d_in[3];
    const float* type_emb = (const float*)d_in[4];
    const float* emb_ln_s = (const float*)d_in[5];
    const float* emb_ln_b = (const float*)d_in[6];
    const float* Wqkv     = (const float*)d_in[7];
    const float* bqkv     = (const float*)d_in[8];
    const float* Wo       = (const float*)d_in[9];
    const float* bo       = (const float*)d_in[10];
    const float* ln1_s    = (const float*)d_in[11];
    const float* ln1_b    = (const float*)d_in[12];
    const float* W1       = (const float*)d_in[13];
    const float* b1       = (const float*)d_in[14];
    const float* W2       = (const float*)d_in[15];
    const float* b2       = (const float*)d_in[16];
    const float* ln2_s    = (const float*)d_in[17];
    const float* ln2_b    = (const float*)d_in[18];
    const float* Wt       = (const float*)d_in[19];
    const float* bt       = (const float*)d_in[20];
    const float* trans    = (const float*)d_in[21];

    char* base = (char*)d_ws;
    size_t off = 0;
    auto alloc = [&](size_t bytes) { void* p = base + off; off += (bytes + 255) & ~(size_t)255; return p; };

    _Float16* wq_h = (_Float16*)alloc(768u * 2304 * 2);
    _Float16* wq_l = (_Float16*)alloc(768u * 2304 * 2);
    _Float16* wo_h = (_Float16*)alloc(768u * 768 * 2);
    _Float16* wo_l = (_Float16*)alloc(768u * 768 * 2);
    _Float16* w1_h = (_Float16*)alloc(768u * 3072 * 2);
    _Float16* w1_l = (_Float16*)alloc(768u * 3072 * 2);
    _Float16* w2_h = (_Float16*)alloc(3072u * 768 * 2);
    _Float16* w2_l = (_Float16*)alloc(3072u * 768 * 2);
    float* h       = (float*)alloc((size_t)MTOK * HH * 4);
    _Float16* hA_h = (_Float16*)alloc((size_t)MTOK * HH * 2);
    _Float16* hA_l = (_Float16*)alloc((size_t)MTOK * HH * 2);
    _Float16* Qp_h = (_Float16*)alloc((size_t)96 * 8192 * 2);
    _Float16* Qp_l = (_Float16*)alloc((size_t)96 * 8192 * 2);
    _Float16* Kp_h = (_Float16*)alloc((size_t)96 * 8192 * 2);
    _Float16* Kp_l = (_Float16*)alloc((size_t)96 * 8192 * 2);
    float* vT      = (float*)alloc((size_t)96 * 8192 * 4);
    _Float16* cA_h = (_Float16*)alloc((size_t)MTOK * HH * 2);
    _Float16* cA_l = (_Float16*)alloc((size_t)MTOK * HH * 2);
    _Float16* gA_h = (_Float16*)alloc((size_t)MTOK * FFI * 2);
    _Float16* gA_l = (_Float16*)alloc((size_t)MTOK * FFI * 2);
    float* parts   = (float*)alloc((size_t)4 * MTOK * HH * 4);
    float* featsb  = (float*)alloc((size_t)MTOK * KT * 4);

    embed_ln_kernel<<<MTOK, 256, 0, stream>>>(sentence, word_emb, pos_emb, type_emb,
                                              emb_ln_s, emb_ln_b, h, hA_h, hA_l);
    for (int l = 0; l < LL; ++l) {
        wconv_kernel<<<3456, 256, 0, stream>>>(
            Wqkv + (size_t)l * 768 * 2304, Wo + (size_t)l * 768 * 768,
            W1 + (size_t)l * 768 * 3072, W2 + (size_t)l * 3072 * 768,
            wq_h, wq_l, wo_h, wo_l, w1_h, w1_l, w2_h, w2_l);
        // QKV transposed: -> Qp/Kp images + vT
        mfma_gemm<2><<<dim3(16, 18), 256, 0, stream>>>(
            wq_h, wq_l, hA_h, hA_l, bqkv + (size_t)l * 2304, vT,
            Qp_h, Qp_l, Kp_h, Kp_l, 2304, 24, 24);
        attn_mfma<<<192, 256, 0, stream>>>(Qp_h, Qp_l, Kp_h, Kp_l, vT, mask, cA_h, cA_l);
        // Wo: normal, split-K 4 -> parts
        mfma_gemm<0><<<dim3(12, 8, 4), 256, 0, stream>>>(
            cA_h, cA_l, wo_h, wo_l, nullptr, parts,
            nullptr, nullptr, nullptr, nullptr, 768, 24, 6);
        add_ln_red_kernel<0><<<MTOK, 256, 0, stream>>>(
            h, parts, bo + (size_t)l * HH, ln1_s + (size_t)l * HH, ln1_b + (size_t)l * HH,
            hA_h, hA_l, nullptr, nullptr, nullptr);
        // FF1 transposed + gelu -> gA planes
        mfma_gemm<3><<<dim3(16, 24), 256, 0, stream>>>(
            w1_h, w1_l, hA_h, hA_l, b1 + (size_t)l * FFI, nullptr,
            gA_h, gA_l, nullptr, nullptr, 3072, 24, 24);
        // FF2: normal, split-K 4 -> parts
        mfma_gemm<0><<<dim3(12, 8, 4), 256, 0, stream>>>(
            gA_h, gA_l, w2_h, w2_l, nullptr, parts,
            nullptr, nullptr, nullptr, nullptr, 768, 96, 24);
        if (l < LL - 1) {
            add_ln_red_kernel<0><<<MTOK, 256, 0, stream>>>(
                h, parts, b2 + (size_t)l * HH, ln2_s + (size_t)l * HH, ln2_b + (size_t)l * HH,
                hA_h, hA_l, nullptr, nullptr, nullptr);
        } else {
            add_ln_red_kernel<1><<<MTOK, 256, 0, stream>>>(
                h, parts, b2 + (size_t)l * HH, ln2_s + (size_t)l * HH, ln2_b + (size_t)l * HH,
                hA_h, hA_l, Wt, bt, featsb);
        }
    }
    viterbi_kernel<<<1, 64, 0, stream>>>(featsb, trans, (float*)d_out);
}